// Round 21
// baseline (286.683 us; speedup 1.0000x reference)
//
#include <hip/hip_runtime.h>
#include <float.h>

#define NPIX 16384    // B*H*W pixels
#define NE   8192     // codebook entries
#define KD   256      // channels
#define HW   1024
#define BCHW 262144
#define NT   8        // N-tiles (128 codes) per wg -> wg spans 1024 codes (slice)
#define DELTA 2.5e-4f // rescue window: bf16 err + 2x key quant + margin
#define KMASK 0xFFFFE000u

typedef __attribute__((ext_vector_type(8))) short short8;
typedef __attribute__((ext_vector_type(4))) short short4v;
typedef __attribute__((ext_vector_type(4))) float f32x4;
typedef __attribute__((ext_vector_type(4))) unsigned int u32x4;
typedef unsigned long long u64;
typedef unsigned int u32;

__device__ __forceinline__ u32 fkey(float f) {
    u32 u = __float_as_uint(f);
    return u ^ ((u >> 31) ? 0xFFFFFFFFu : 0x80000000u);
}
__device__ __forceinline__ short bf16rne(float f) {
    u32 u = __float_as_uint(f);
    u += 0x7FFFu + ((u >> 16) & 1u);
    return (short)(u >> 16);
}
__device__ __forceinline__ float kval(u32 pk) {   // packed key -> quantized value
    return __uint_as_float(pk & KMASK);
}

#define GLDS(gp, lp) __builtin_amdgcn_global_load_lds( \
    (const __attribute__((address_space(1))) void*)(gp), \
    (__attribute__((address_space(3))) void*)(lp), 16, 0, 0)

// ---------------------------------------------------------------------------
// prep: codebook -> bf16 AND e2[n] = ||e_n||^2. One wave per row.
// ---------------------------------------------------------------------------
__global__ void vq_prep(const float* __restrict__ cb, short* __restrict__ eh,
                        float* __restrict__ e2) {
    const int row  = (blockIdx.x * 256 + threadIdx.x) >> 6;
    const int lane = threadIdx.x & 63;
    const f32x4 v = *(const f32x4*)(cb + (size_t)row * KD + lane * 4);
    short4v h;
    h[0] = bf16rne(v[0]); h[1] = bf16rne(v[1]);
    h[2] = bf16rne(v[2]); h[3] = bf16rne(v[3]);
    *(short4v*)(eh + (size_t)row * KD + lane * 4) = h;
    float s = v[0]*v[0] + v[1]*v[1] + v[2]*v[2] + v[3]*v[3];
    #pragma unroll
    for (int m = 1; m < 64; m <<= 1) s += __shfl_xor(s, m);
    if (lane == 0) e2[row] = s;
}

// ---------------------------------------------------------------------------
// z [b][k][hw] fp32 -> zh [p][k] bf16 (transpose via LDS)
// ---------------------------------------------------------------------------
__global__ void vq_zh(const float* __restrict__ z, short* __restrict__ zh) {
    __shared__ float ts[64][65];
    const int b   = blockIdx.z;
    const int k0  = blockIdx.y * 64;
    const int hw0 = blockIdx.x * 64;
    const int tid = threadIdx.x;
    const int pl  = tid & 63, kk = tid >> 6;
    #pragma unroll
    for (int i = 0; i < 16; ++i) {
        const int k = kk + 4 * i;
        ts[k][pl] = z[b * BCHW + (k0 + k) * HW + hw0 + pl];
    }
    __syncthreads();
    const int tx = tid & 15, ty = tid >> 4;
    #pragma unroll
    for (int j = 0; j < 4; ++j) {
        const int p = ty + 16 * j;
        short4v v;
        #pragma unroll
        for (int q = 0; q < 4; ++q) v[q] = bf16rne(ts[tx * 4 + q][p]);
        *(short4v*)(zh + (size_t)(b * HW + hw0 + p) * KD + k0 + tx * 4) = v;
    }
}

// ---------------------------------------------------------------------------
// Fused GEMM + per-(pixel, HALF-slice) top-4 tracking.
// R21: register diet for 3 waves/SIMD. A STREAMED from global (L1-hot)
// with a 2-deep register buffer (32 VGPR) instead of the 64-VGPR afr
// cache; B via LDS with R18's proven counted-vmcnt schedule (4 static
// buffers, 2-deep prefetch, sched_barrier + raw s_barrier). Per step:
// A(t+1) loads issued BEFORE B(t+2) stage so the compiler's A-wait does
// not force B prefetch completion (vmcnt counts in issue order).
// vmcnt(6) = A(t)x4 + B(t+1)x2 newer than B(t).
// ---------------------------------------------------------------------------
__global__ __launch_bounds__(256, 3) void vq_gemm(
    const short* __restrict__ zh, const short* __restrict__ eh,
    u32* __restrict__ best4)
{
    __shared__ short Bs[4][4096];   // [buf][128 rows x 32 k]  (32 KB)

    const int tid  = threadIdx.x;
    const int lane = tid & 63;
    const int w    = tid >> 6;
    const int wm   = w >> 1, wn = w & 1;
    const int p0   = blockIdx.x * 128;
    const int nb0  = blockIdx.y * (NT * 128);

    const int sr = lane >> 2;
    const int ss = (lane & 3) ^ ((sr >> 1) & 3);
    const int q   = lane >> 4;
    const int rsw = ((lane & 15) >> 1) & 3;

    u32 b1[4][4], b2[4][4];
    #pragma unroll
    for (int m = 0; m < 4; ++m)
        #pragma unroll
        for (int r = 0; r < 4; ++r) { b1[m][r] = 0xFFFFFFFFu; b2[m][r] = 0xFFFFFFFFu; }

    // A row byte-bases (per m); k-window added per step
    size_t arow[4];
    #pragma unroll
    for (int m = 0; m < 4; ++m)
        arow[m] = (size_t)(p0 + wm * 64 + m * 16 + (lane & 15)) * KD + q * 8;

    short8 areg[2][4];
    #define LOADA(t_, buf_) do {                                               \
        _Pragma("unroll")                                                      \
        for (int m_ = 0; m_ < 4; ++m_)                                         \
            areg[buf_][m_] = *(const short8*)(zh + arow[m_] + (t_) * 32);      \
    } while (0)

    // stage B tile (nt_, t_) into buffer buf_ (2 GLDS per wave)
    #define STAGEB(nt_, t_, buf_) do {                                         \
        const int k0_ = (t_) * 32;                                             \
        const int n0_ = nb0 + (nt_) * 128;                                     \
        _Pragma("unroll")                                                      \
        for (int i_ = 0; i_ < 2; ++i_) {                                       \
            const int rb_ = w * 32 + i_ * 16;                                  \
            GLDS(eh + (size_t)(n0_ + rb_ + sr) * KD + k0_ + ss * 8,            \
                 &Bs[buf_][rb_ * 32]);                                         \
        }                                                                      \
    } while (0)

    f32x4 acc[4][4];

    STAGEB(0, 0, 0);
    STAGEB(0, 1, 1);
    LOADA(0, 0);

    #pragma unroll 1
    for (int nt = 0; nt < NT; ++nt) {
        const bool lastnt = (nt == NT - 1);
        #pragma unroll
        for (int t = 0; t < 8; ++t) {
            // B(t) landed (own 2 loads); 6 newer ops may stay in flight
            if (lastnt && t == 7) asm volatile("s_waitcnt vmcnt(0)" ::: "memory");
            else                  asm volatile("s_waitcnt vmcnt(6)" ::: "memory");
            __builtin_amdgcn_sched_barrier(0);
            __builtin_amdgcn_s_barrier();   // tile (nt,t) visible to all waves

            // A stream first (so its wait never forces B prefetch), B second
            if (t < 7)        { LOADA(t + 1, (t + 1) & 1); }
            else if (!lastnt) { LOADA(0, 0); }
            if (t < 6)        { STAGEB(nt, t + 2, (t + 2) & 3); }
            else if (!lastnt) { STAGEB(nt + 1, t - 6, (t - 6) & 3); }

            if (t == 0) {
                #pragma unroll
                for (int m = 0; m < 4; ++m)
                    #pragma unroll
                    for (int nf = 0; nf < 4; ++nf)
                        acc[m][nf] = (f32x4){0.f, 0.f, 0.f, 0.f};
            }

            short8 bfv[4];
            #pragma unroll
            for (int nf = 0; nf < 4; ++nf) {
                const int row = wn * 64 + nf * 16 + (lane & 15);
                bfv[nf] = *(const short8*)&Bs[t & 3][row * 32 + ((q ^ rsw) * 8)];
            }
            #pragma unroll
            for (int m = 0; m < 4; ++m)
                #pragma unroll
                for (int nf = 0; nf < 4; ++nf)
                    acc[m][nf] = __builtin_amdgcn_mfma_f32_16x16x32_bf16(
                        areg[t & 1][m], bfv[nf], acc[m][nf], 0, 0, 0);

            if (t == 7) {
                // ---- register-only best-2 merge (no shfl, no globals) ----
                const u32 nbase = (u32)(nb0 + nt * 128 + wn * 64 + (lane & 15));
                #pragma unroll
                for (int m = 0; m < 4; ++m) {
                    #pragma unroll
                    for (int r = 0; r < 4; ++r) {
                        u32 pk0 = (__float_as_uint(0.0625f - acc[m][0][r]) & KMASK) | (nbase);
                        u32 pk1 = (__float_as_uint(0.0625f - acc[m][1][r]) & KMASK) | (nbase + 16u);
                        u32 pk2 = (__float_as_uint(0.0625f - acc[m][2][r]) & KMASK) | (nbase + 32u);
                        u32 pk3 = (__float_as_uint(0.0625f - acc[m][3][r]) & KMASK) | (nbase + 48u);
                        const u32 lo01 = min(pk0, pk1), hi01 = max(pk0, pk1);
                        const u32 lo23 = min(pk2, pk3), hi23 = max(pk2, pk3);
                        const u32 m1 = min(lo01, lo23);
                        const u32 m2 = min(max(lo01, lo23), min(hi01, hi23));
                        const u32 nb1 = min(b1[m][r], m1);
                        const u32 nb2 = min(max(b1[m][r], m1), min(b2[m][r], m2));
                        b1[m][r] = nb1; b2[m][r] = nb2;
                    }
                }
            }
        }
    }
    #undef STAGEB
    #undef LOADA

    // ---- wg-end: top-4 of this wave's 32-key lane-union per pixel ----
    const int g = lane >> 4;
    const int hs = blockIdx.y * 2 + wn;          // half-slice: single writer
    #pragma unroll
    for (int m = 0; m < 4; ++m) {
        #pragma unroll
        for (int r = 0; r < 4; ++r) {
            u32 a = b1[m][r], b = b2[m][r];
            u32 o[4];
            #pragma unroll
            for (int j = 0; j < 4; ++j) {
                u32 mm = a;
                #pragma unroll
                for (int msk = 1; msk < 16; msk <<= 1)
                    mm = min(mm, (u32)__shfl_xor((int)mm, msk));
                o[j] = mm;
                if (a == mm) { a = b; b = 0xFFFFFFFFu; }
            }
            if ((lane & 15) == 0) {
                const int prow = p0 + wm * 64 + m * 16 + g * 4 + r;
                u32x4 ov; ov[0] = o[0]; ov[1] = o[1]; ov[2] = o[2]; ov[3] = o[3];
                *(u32x4*)&best4[((size_t)prow * 16 + hs) * 4] = ov;
            }
        }
    }
}

// ---------------------------------------------------------------------------
// exact (parallel): one wg per 16 pixels, 256 threads. Unchanged from R15.
// ---------------------------------------------------------------------------
__global__ __launch_bounds__(256) void vq_exact(
    const float* __restrict__ z, const float* __restrict__ cb,
    const float* __restrict__ e2, const u32* __restrict__ best4,
    u64* __restrict__ final_)
{
    __shared__ float zb[16][260];
    __shared__ u32 work[1024];     // (pix<<13) | n
    __shared__ u32 scans[256];     // (pix<<4) | hsx
    __shared__ int nwork, nscan;

    const int tid = threadIdx.x;
    const int g0  = blockIdx.x * 16;
    const int bb  = g0 >> 10, hw0 = g0 & 1023;
    const int pix = tid >> 4;
    const int hsx = tid & 15;

    if (tid == 0) { nwork = 0; nscan = 0; }
    __syncthreads();

    // Phase A ------------------------------------------------------------
    const u32x4 kv = *(const u32x4*)&best4[((size_t)(g0 + pix) * 16 + hsx) * 4];
    const u32 lmin = min(min(kv[0], kv[1]), min(kv[2], kv[3]));
    u32 mn = lmin;
    #pragma unroll
    for (int m = 1; m < 16; m <<= 1) mn = min(mn, (u32)__shfl_xor((int)mn, m));
    const float thr = kval(mn) + DELTA;
    const int c4 = (kval(kv[0]) <= thr ? 1 : 0) + (kval(kv[1]) <= thr ? 1 : 0)
                 + (kval(kv[2]) <= thr ? 1 : 0) + (kval(kv[3]) <= thr ? 1 : 0);
    int cnt = c4;
    #pragma unroll
    for (int m = 1; m < 16; m <<= 1) cnt += __shfl_xor(cnt, m);
    const int susp = (c4 == 4) ? 1 : 0;
    int anysusp = susp;
    #pragma unroll
    for (int m = 1; m < 16; m <<= 1) anysusp += __shfl_xor(anysusp, m);

    if (cnt == 1 && anysusp == 0) {
        if (lmin == mn) final_[g0 + pix] = (u64)(mn & 8191u);
    } else {
        if (c4 > 0) {
            const int base = atomicAdd(&nwork, c4);
            int k = 0;
            #pragma unroll
            for (int j = 0; j < 4; ++j)
                if (kval(kv[j]) <= thr)
                    work[base + (k++)] = ((u32)pix << 13) | (kv[j] & 8191u);
        }
        if (susp) scans[atomicAdd(&nscan, 1)] = ((u32)pix << 4) | (u32)hsx;
    }
    __syncthreads();
    const int nw = nwork, ns = nscan;
    if (nw == 0 && ns == 0) return;

    // Phase B: stage the 16-pixel z block coalesced ------------------------
    #pragma unroll
    for (int i = 0; i < 16; ++i) {
        const int idx = i * 256 + tid;
        const int c = idx >> 4, px = idx & 15;
        zb[px][c] = z[(size_t)bb * BCHW + (size_t)c * HW + hw0 + px];
    }
    __syncthreads();

    // Phase C: one thread per passer candidate ----------------------------
    for (int i = tid; i < nw; i += 256) {
        const u32 e = work[i];
        const int px = (int)(e >> 13), n = (int)(e & 8191u);
        const float* er = cb + (size_t)n * KD;
        float acc = 0.f;
        #pragma unroll 4
        for (int k = 0; k < KD; k += 4) {
            const f32x4 zv = *(const f32x4*)&zb[px][k];
            const f32x4 ev = *(const f32x4*)(er + k);
            acc += zv[0]*ev[0] + zv[1]*ev[1] + zv[2]*ev[2] + zv[3]*ev[3];
        }
        const float s = 0.5f * e2[n] - acc;
        atomicMin(&final_[g0 + px], ((u64)fkey(s) << 32) | (u32)n);
    }

    // Phase D: suspect half-slice scans (rare) ----------------------------
    for (int si = 0; si < ns; ++si) {
        const u32 e = scans[si];
        const int px = (int)(e >> 4), hx = (int)(e & 15u);
        u64 bku = ~0ULL;
        #pragma unroll
        for (int h = 0; h < 2; ++h) {
            const int ci = tid + h * 256;
            const int n = (hx >> 1) * 1024 + (ci >> 6) * 128
                        + (hx & 1) * 64 + (ci & 63);
            const float* er = cb + (size_t)n * KD;
            float acc = 0.f;
            #pragma unroll 4
            for (int k = 0; k < KD; k += 4) {
                const f32x4 zv = *(const f32x4*)&zb[px][k];
                const f32x4 ev = *(const f32x4*)(er + k);
                acc += zv[0]*ev[0] + zv[1]*ev[1] + zv[2]*ev[2] + zv[3]*ev[3];
            }
            const float s = 0.5f * e2[n] - acc;
            const u64 pk = ((u64)fkey(s) << 32) | (u32)n;
            bku = min(bku, pk);
        }
        #pragma unroll
        for (int m = 1; m < 64; m <<= 1) {
            const u64 o = (u64)__shfl_xor((long long)bku, m);
            bku = min(bku, o);
        }
        if ((tid & 63) == 0) atomicMin(&final_[g0 + px], bku);
    }
}

// ---------------------------------------------------------------------------
// Output kernel, tile-transposed.
// ---------------------------------------------------------------------------
__global__ __launch_bounds__(256) void vq_out_kernel(
    const float* __restrict__ z, const float* __restrict__ cb,
    const u64* __restrict__ final_, float* __restrict__ out,
    float* __restrict__ idxf, float* __restrict__ loss)
{
    __shared__ float zq[32][257];
    __shared__ int   nidx[32];

    const int tid = threadIdx.x;
    const int p0  = blockIdx.x * 32;
    const int bb  = p0 >> 10;
    const int hw0 = p0 & 1023;

    if (tid < 32) {
        const int n = (int)((u32)final_[p0 + tid] & 8191u);
        nidx[tid] = n;
        idxf[p0 + tid] = (float)n;
    }
    __syncthreads();

    {
        const int r = tid >> 3, i = tid & 7;
        const float* src = cb + (size_t)nidx[r] * KD;
        #pragma unroll
        for (int j = 0; j < 8; ++j) {
            const int col = i * 4 + j * 32;
            const f32x4 v = *(const f32x4*)(src + col);
            zq[r][col + 0] = v[0]; zq[r][col + 1] = v[1];
            zq[r][col + 2] = v[2]; zq[r][col + 3] = v[3];
        }
    }
    __syncthreads();

    const int p4 = (tid & 7) * 4;
    const int cg = tid >> 3;
    float ls = 0.f;
    #pragma unroll
    for (int ii = 0; ii < 8; ++ii) {
        const int c = cg + 32 * ii;
        const size_t e = (size_t)bb * BCHW + (size_t)c * HW + hw0 + p4;
        const f32x4 zv = *(const f32x4*)(z + e);
        f32x4 v;
        v[0] = zq[p4 + 0][c]; v[1] = zq[p4 + 1][c];
        v[2] = zq[p4 + 2][c]; v[3] = zq[p4 + 3][c];
        *(f32x4*)(out + e) = v;
        const float d0 = v[0] - zv[0], d1 = v[1] - zv[1];
        const float d2 = v[2] - zv[2], d3 = v[3] - zv[3];
        ls += d0 * d0 + d1 * d1 + d2 * d2 + d3 * d3;
    }
    #pragma unroll
    for (int m = 1; m < 64; m <<= 1) ls += __shfl_xor(ls, m);
    if ((tid & 63) == 0) atomicAdd(loss, ls * (1.25f / 4194304.f));
}

// ---------------------------------------------------------------------------
extern "C" void kernel_launch(void* const* d_in, const int* in_sizes, int n_in,
                              void* d_out, int out_size, void* d_ws, size_t ws_size,
                              hipStream_t stream) {
    const float* z  = (const float*)d_in[0];
    const float* cb = (const float*)d_in[1];
    float* out  = (float*)d_out;
    float* idxf = out + 4194304;
    float* loss = out + 4210688;
    // scratch inside the z_q region of d_out (fully overwritten at the end):
    char* ob = (char*)d_out;
    short* zh    = (short*)ob;                    // [0 .. 8MB)   bf16 z [p][k]
    short* eh    = (short*)(ob + 8388608);        // [8 .. 12MB)  bf16 codebook
    u32*   best4 = (u32*)(ob + 12582912);         // [12 .. 16MB) 16384 x 16 x 4 u32

    char* ws = (char*)d_ws;
    u64*   final_ = (u64*)ws;                // 128 KB @ 0
    float* e2     = (float*)(ws + 131072);   // 32 KB

    hipMemsetAsync(final_, 0xFF, 131072, stream);
    hipMemsetAsync(loss, 0, 4, stream);

    vq_prep<<<2048, 256, 0, stream>>>(cb, eh, e2);
    vq_zh<<<dim3(16, 4, 16), 256, 0, stream>>>(z, zh);
    vq_gemm<<<dim3(NPIX / 128, NE / (NT * 128)), 256, 0, stream>>>(zh, eh, best4);
    vq_exact<<<NPIX / 16, 256, 0, stream>>>(z, cb, e2, best4, final_);
    vq_out_kernel<<<NPIX / 32, 256, 0, stream>>>(z, cb, final_, out, idxf, loss);
}

// Round 22
// 198.017 us; speedup vs baseline: 1.4478x; 1.4478x over previous
//
#include <hip/hip_runtime.h>
#include <float.h>

#define NPIX 16384    // B*H*W pixels
#define NE   8192     // codebook entries
#define KD   256      // channels
#define HW   1024
#define BCHW 262144
#define NT   16       // N-tiles (128 codes) per wg -> wg spans 2048 codes (2 slices)
#define DELTA 2.5e-4f // rescue window: bf16 err + 2x key quant + margin
#define KMASK 0xFFFFE000u

typedef __attribute__((ext_vector_type(8))) short short8;
typedef __attribute__((ext_vector_type(4))) short short4v;
typedef __attribute__((ext_vector_type(4))) float f32x4;
typedef __attribute__((ext_vector_type(4))) unsigned int u32x4;
typedef unsigned long long u64;
typedef unsigned int u32;

__device__ __forceinline__ u32 fkey(float f) {
    u32 u = __float_as_uint(f);
    return u ^ ((u >> 31) ? 0xFFFFFFFFu : 0x80000000u);
}
__device__ __forceinline__ short bf16rne(float f) {
    u32 u = __float_as_uint(f);
    u += 0x7FFFu + ((u >> 16) & 1u);
    return (short)(u >> 16);
}
__device__ __forceinline__ float kval(u32 pk) {   // packed key -> quantized value
    return __uint_as_float(pk & KMASK);
}

#define GLDS(gp, lp) __builtin_amdgcn_global_load_lds( \
    (const __attribute__((address_space(1))) void*)(gp), \
    (__attribute__((address_space(3))) void*)(lp), 16, 0, 0)

// ---------------------------------------------------------------------------
// prep: codebook -> bf16 AND e2[n] = ||e_n||^2. One wave per row.
// ---------------------------------------------------------------------------
__global__ void vq_prep(const float* __restrict__ cb, short* __restrict__ eh,
                        float* __restrict__ e2) {
    const int row  = (blockIdx.x * 256 + threadIdx.x) >> 6;
    const int lane = threadIdx.x & 63;
    const f32x4 v = *(const f32x4*)(cb + (size_t)row * KD + lane * 4);
    short4v h;
    h[0] = bf16rne(v[0]); h[1] = bf16rne(v[1]);
    h[2] = bf16rne(v[2]); h[3] = bf16rne(v[3]);
    *(short4v*)(eh + (size_t)row * KD + lane * 4) = h;
    float s = v[0]*v[0] + v[1]*v[1] + v[2]*v[2] + v[3]*v[3];
    #pragma unroll
    for (int m = 1; m < 64; m <<= 1) s += __shfl_xor(s, m);
    if (lane == 0) e2[row] = s;
}

// ---------------------------------------------------------------------------
// z [b][k][hw] fp32 -> zh [p][k] bf16 (transpose via LDS)
// ---------------------------------------------------------------------------
__global__ void vq_zh(const float* __restrict__ z, short* __restrict__ zh) {
    __shared__ float ts[64][65];
    const int b   = blockIdx.z;
    const int k0  = blockIdx.y * 64;
    const int hw0 = blockIdx.x * 64;
    const int tid = threadIdx.x;
    const int pl  = tid & 63, kk = tid >> 6;
    #pragma unroll
    for (int i = 0; i < 16; ++i) {
        const int k = kk + 4 * i;
        ts[k][pl] = z[b * BCHW + (k0 + k) * HW + hw0 + pl];
    }
    __syncthreads();
    const int tx = tid & 15, ty = tid >> 4;
    #pragma unroll
    for (int j = 0; j < 4; ++j) {
        const int p = ty + 16 * j;
        short4v v;
        #pragma unroll
        for (int q = 0; q < 4; ++q) v[q] = bf16rne(ts[tx * 4 + q][p]);
        *(short4v*)(zh + (size_t)(b * HW + hw0 + p) * KD + k0 + tx * 4) = v;
    }
}

// ---------------------------------------------------------------------------
// Fused GEMM + per-(pixel, HALF-slice) top-4 tracking.
// R22 = R18 schedule (A in registers once per wg, B via LDS, counted
// vmcnt(2), 4 static buffers, sched_barrier + raw s_barrier) with NT=16:
// each wg covers TWO 1024-code slices -> grid 128x4 = 512 wgs = exactly
// one resident batch (2 wgs/CU). Top-4 extracted+stored at nt==7 and
// nt==15 (hs = blockIdx.y*4 + (nt>>3)*2 + wn keeps one writer per
// (pixel, half-slice)); b1/b2 reset between slices.
// ---------------------------------------------------------------------------
__global__ __launch_bounds__(256, 2) void vq_gemm(
    const short* __restrict__ zh, const short* __restrict__ eh,
    u32* __restrict__ best4)
{
    __shared__ short Bs[4][4096];   // [buf][128 rows x 32 k]  (32 KB total)

    const int tid  = threadIdx.x;
    const int lane = tid & 63;
    const int w    = tid >> 6;
    const int wm   = w >> 1, wn = w & 1;
    const int p0   = blockIdx.x * 128;
    const int nb0  = blockIdx.y * (NT * 128);

    const int sr = lane >> 2;
    const int ss = (lane & 3) ^ ((sr >> 1) & 3);
    const int q   = lane >> 4;
    const int rsw = ((lane & 15) >> 1) & 3;

    u32 b1[4][4], b2[4][4];
    #pragma unroll
    for (int m = 0; m < 4; ++m)
        #pragma unroll
        for (int r = 0; r < 4; ++r) { b1[m][r] = 0xFFFFFFFFu; b2[m][r] = 0xFFFFFFFFu; }

    // ---- A-fragments: direct global -> register, once per wg ----
    short8 afr[4][8];
    #pragma unroll
    for (int m = 0; m < 4; ++m) {
        const size_t rowb = (size_t)(p0 + wm * 64 + m * 16 + (lane & 15)) * KD;
        #pragma unroll
        for (int ks = 0; ks < 8; ++ks)
            afr[m][ks] = *(const short8*)(zh + rowb + ks * 32 + q * 8);
    }
    // drain A loads so the loop's counted vmcnt tracks ONLY B stages
    asm volatile("s_waitcnt vmcnt(0)" ::: "memory");

    // stage B tile (nt_, t_) into buffer buf_ (2 GLDS per wave)
    #define STAGEB(nt_, t_, buf_) do {                                         \
        const int k0_ = (t_) * 32;                                             \
        const int n0_ = nb0 + (nt_) * 128;                                     \
        _Pragma("unroll")                                                      \
        for (int i_ = 0; i_ < 2; ++i_) {                                       \
            const int rb_ = w * 32 + i_ * 16;                                  \
            GLDS(eh + (size_t)(n0_ + rb_ + sr) * KD + k0_ + ss * 8,            \
                 &Bs[buf_][rb_ * 32]);                                         \
        }                                                                      \
    } while (0)

    f32x4 acc[4][4];

    STAGEB(0, 0, 0);
    STAGEB(0, 1, 1);

    #pragma unroll 1
    for (int nt = 0; nt < NT; ++nt) {
        const bool lastnt = (nt == NT - 1);
        #pragma unroll
        for (int t = 0; t < 8; ++t) {
            // wait: tile (nt,t)'s 2 loads complete; the 2 newer stay in flight
            if (lastnt && t == 7) asm volatile("s_waitcnt vmcnt(0)" ::: "memory");
            else                  asm volatile("s_waitcnt vmcnt(2)" ::: "memory");
            __builtin_amdgcn_sched_barrier(0);
            __builtin_amdgcn_s_barrier();   // tile (nt,t) visible to all waves

            if (t < 6)        { STAGEB(nt, t + 2, (t + 2) & 3); }
            else if (!lastnt) { STAGEB(nt + 1, t - 6, (t - 6) & 3); }

            if (t == 0) {
                #pragma unroll
                for (int m = 0; m < 4; ++m)
                    #pragma unroll
                    for (int nf = 0; nf < 4; ++nf)
                        acc[m][nf] = (f32x4){0.f, 0.f, 0.f, 0.f};
            }

            short8 bfv[4];
            #pragma unroll
            for (int nf = 0; nf < 4; ++nf) {
                const int row = wn * 64 + nf * 16 + (lane & 15);
                bfv[nf] = *(const short8*)&Bs[t & 3][row * 32 + ((q ^ rsw) * 8)];
            }
            #pragma unroll
            for (int m = 0; m < 4; ++m)
                #pragma unroll
                for (int nf = 0; nf < 4; ++nf)
                    acc[m][nf] = __builtin_amdgcn_mfma_f32_16x16x32_bf16(
                        afr[m][t], bfv[nf], acc[m][nf], 0, 0, 0);

            if (t == 7) {
                // ---- register-only best-2 merge (no shfl, no globals) ----
                const u32 nbase = (u32)(nb0 + nt * 128 + wn * 64 + (lane & 15));
                #pragma unroll
                for (int m = 0; m < 4; ++m) {
                    #pragma unroll
                    for (int r = 0; r < 4; ++r) {
                        u32 pk0 = (__float_as_uint(0.0625f - acc[m][0][r]) & KMASK) | (nbase);
                        u32 pk1 = (__float_as_uint(0.0625f - acc[m][1][r]) & KMASK) | (nbase + 16u);
                        u32 pk2 = (__float_as_uint(0.0625f - acc[m][2][r]) & KMASK) | (nbase + 32u);
                        u32 pk3 = (__float_as_uint(0.0625f - acc[m][3][r]) & KMASK) | (nbase + 48u);
                        const u32 lo01 = min(pk0, pk1), hi01 = max(pk0, pk1);
                        const u32 lo23 = min(pk2, pk3), hi23 = max(pk2, pk3);
                        const u32 m1 = min(lo01, lo23);
                        const u32 m2 = min(max(lo01, lo23), min(hi01, hi23));
                        const u32 nb1 = min(b1[m][r], m1);
                        const u32 nb2 = min(max(b1[m][r], m1), min(b2[m][r], m2));
                        b1[m][r] = nb1; b2[m][r] = nb2;
                    }
                }
            }
        }

        if ((nt & 7) == 7) {
            // ---- per-slice: top-4 of this wave's 32-key lane-union ----
            // (ascending; unique keys -> exactly one lane consumes/round)
            const int g = lane >> 4;
            const int hs = blockIdx.y * 4 + (nt >> 3) * 2 + wn;  // 1 writer
            #pragma unroll
            for (int m = 0; m < 4; ++m) {
                #pragma unroll
                for (int r = 0; r < 4; ++r) {
                    u32 a = b1[m][r], b = b2[m][r];
                    u32 o[4];
                    #pragma unroll
                    for (int j = 0; j < 4; ++j) {
                        u32 mm = a;
                        #pragma unroll
                        for (int msk = 1; msk < 16; msk <<= 1)
                            mm = min(mm, (u32)__shfl_xor((int)mm, msk));
                        o[j] = mm;
                        if (a == mm) { a = b; b = 0xFFFFFFFFu; }
                    }
                    if ((lane & 15) == 0) {
                        const int prow = p0 + wm * 64 + m * 16 + g * 4 + r;
                        u32x4 ov; ov[0]=o[0]; ov[1]=o[1]; ov[2]=o[2]; ov[3]=o[3];
                        *(u32x4*)&best4[((size_t)prow * 16 + hs) * 4] = ov;
                    }
                    b1[m][r] = 0xFFFFFFFFu;   // reset for next slice
                    b2[m][r] = 0xFFFFFFFFu;
                }
            }
        }
    }
    #undef STAGEB
}

// ---------------------------------------------------------------------------
// exact (parallel): one wg per 16 pixels, 256 threads. Unchanged from R15.
// ---------------------------------------------------------------------------
__global__ __launch_bounds__(256) void vq_exact(
    const float* __restrict__ z, const float* __restrict__ cb,
    const float* __restrict__ e2, const u32* __restrict__ best4,
    u64* __restrict__ final_)
{
    __shared__ float zb[16][260];
    __shared__ u32 work[1024];     // (pix<<13) | n
    __shared__ u32 scans[256];     // (pix<<4) | hsx
    __shared__ int nwork, nscan;

    const int tid = threadIdx.x;
    const int g0  = blockIdx.x * 16;
    const int bb  = g0 >> 10, hw0 = g0 & 1023;
    const int pix = tid >> 4;
    const int hsx = tid & 15;

    if (tid == 0) { nwork = 0; nscan = 0; }
    __syncthreads();

    // Phase A ------------------------------------------------------------
    const u32x4 kv = *(const u32x4*)&best4[((size_t)(g0 + pix) * 16 + hsx) * 4];
    const u32 lmin = min(min(kv[0], kv[1]), min(kv[2], kv[3]));
    u32 mn = lmin;
    #pragma unroll
    for (int m = 1; m < 16; m <<= 1) mn = min(mn, (u32)__shfl_xor((int)mn, m));
    const float thr = kval(mn) + DELTA;
    const int c4 = (kval(kv[0]) <= thr ? 1 : 0) + (kval(kv[1]) <= thr ? 1 : 0)
                 + (kval(kv[2]) <= thr ? 1 : 0) + (kval(kv[3]) <= thr ? 1 : 0);
    int cnt = c4;
    #pragma unroll
    for (int m = 1; m < 16; m <<= 1) cnt += __shfl_xor(cnt, m);
    const int susp = (c4 == 4) ? 1 : 0;
    int anysusp = susp;
    #pragma unroll
    for (int m = 1; m < 16; m <<= 1) anysusp += __shfl_xor(anysusp, m);

    if (cnt == 1 && anysusp == 0) {
        if (lmin == mn) final_[g0 + pix] = (u64)(mn & 8191u);
    } else {
        if (c4 > 0) {
            const int base = atomicAdd(&nwork, c4);
            int k = 0;
            #pragma unroll
            for (int j = 0; j < 4; ++j)
                if (kval(kv[j]) <= thr)
                    work[base + (k++)] = ((u32)pix << 13) | (kv[j] & 8191u);
        }
        if (susp) scans[atomicAdd(&nscan, 1)] = ((u32)pix << 4) | (u32)hsx;
    }
    __syncthreads();
    const int nw = nwork, ns = nscan;
    if (nw == 0 && ns == 0) return;

    // Phase B: stage the 16-pixel z block coalesced ------------------------
    #pragma unroll
    for (int i = 0; i < 16; ++i) {
        const int idx = i * 256 + tid;
        const int c = idx >> 4, px = idx & 15;
        zb[px][c] = z[(size_t)bb * BCHW + (size_t)c * HW + hw0 + px];
    }
    __syncthreads();

    // Phase C: one thread per passer candidate ----------------------------
    for (int i = tid; i < nw; i += 256) {
        const u32 e = work[i];
        const int px = (int)(e >> 13), n = (int)(e & 8191u);
        const float* er = cb + (size_t)n * KD;
        float acc = 0.f;
        #pragma unroll 4
        for (int k = 0; k < KD; k += 4) {
            const f32x4 zv = *(const f32x4*)&zb[px][k];
            const f32x4 ev = *(const f32x4*)(er + k);
            acc += zv[0]*ev[0] + zv[1]*ev[1] + zv[2]*ev[2] + zv[3]*ev[3];
        }
        const float s = 0.5f * e2[n] - acc;
        atomicMin(&final_[g0 + px], ((u64)fkey(s) << 32) | (u32)n);
    }

    // Phase D: suspect half-slice scans (rare) ----------------------------
    for (int si = 0; si < ns; ++si) {
        const u32 e = scans[si];
        const int px = (int)(e >> 4), hx = (int)(e & 15u);
        u64 bku = ~0ULL;
        #pragma unroll
        for (int h = 0; h < 2; ++h) {
            const int ci = tid + h * 256;
            const int n = (hx >> 1) * 1024 + (ci >> 6) * 128
                        + (hx & 1) * 64 + (ci & 63);
            const float* er = cb + (size_t)n * KD;
            float acc = 0.f;
            #pragma unroll 4
            for (int k = 0; k < KD; k += 4) {
                const f32x4 zv = *(const f32x4*)&zb[px][k];
                const f32x4 ev = *(const f32x4*)(er + k);
                acc += zv[0]*ev[0] + zv[1]*ev[1] + zv[2]*ev[2] + zv[3]*ev[3];
            }
            const float s = 0.5f * e2[n] - acc;
            const u64 pk = ((u64)fkey(s) << 32) | (u32)n;
            bku = min(bku, pk);
        }
        #pragma unroll
        for (int m = 1; m < 64; m <<= 1) {
            const u64 o = (u64)__shfl_xor((long long)bku, m);
            bku = min(bku, o);
        }
        if ((tid & 63) == 0) atomicMin(&final_[g0 + px], bku);
    }
}

// ---------------------------------------------------------------------------
// Output kernel, tile-transposed.
// ---------------------------------------------------------------------------
__global__ __launch_bounds__(256) void vq_out_kernel(
    const float* __restrict__ z, const float* __restrict__ cb,
    const u64* __restrict__ final_, float* __restrict__ out,
    float* __restrict__ idxf, float* __restrict__ loss)
{
    __shared__ float zq[32][257];
    __shared__ int   nidx[32];

    const int tid = threadIdx.x;
    const int p0  = blockIdx.x * 32;
    const int bb  = p0 >> 10;
    const int hw0 = p0 & 1023;

    if (tid < 32) {
        const int n = (int)((u32)final_[p0 + tid] & 8191u);
        nidx[tid] = n;
        idxf[p0 + tid] = (float)n;
    }
    __syncthreads();

    {
        const int r = tid >> 3, i = tid & 7;
        const float* src = cb + (size_t)nidx[r] * KD;
        #pragma unroll
        for (int j = 0; j < 8; ++j) {
            const int col = i * 4 + j * 32;
            const f32x4 v = *(const f32x4*)(src + col);
            zq[r][col + 0] = v[0]; zq[r][col + 1] = v[1];
            zq[r][col + 2] = v[2]; zq[r][col + 3] = v[3];
        }
    }
    __syncthreads();

    const int p4 = (tid & 7) * 4;
    const int cg = tid >> 3;
    float ls = 0.f;
    #pragma unroll
    for (int ii = 0; ii < 8; ++ii) {
        const int c = cg + 32 * ii;
        const size_t e = (size_t)bb * BCHW + (size_t)c * HW + hw0 + p4;
        const f32x4 zv = *(const f32x4*)(z + e);
        f32x4 v;
        v[0] = zq[p4 + 0][c]; v[1] = zq[p4 + 1][c];
        v[2] = zq[p4 + 2][c]; v[3] = zq[p4 + 3][c];
        *(f32x4*)(out + e) = v;
        const float d0 = v[0] - zv[0], d1 = v[1] - zv[1];
        const float d2 = v[2] - zv[2], d3 = v[3] - zv[3];
        ls += d0 * d0 + d1 * d1 + d2 * d2 + d3 * d3;
    }
    #pragma unroll
    for (int m = 1; m < 64; m <<= 1) ls += __shfl_xor(ls, m);
    if ((tid & 63) == 0) atomicAdd(loss, ls * (1.25f / 4194304.f));
}

// ---------------------------------------------------------------------------
extern "C" void kernel_launch(void* const* d_in, const int* in_sizes, int n_in,
                              void* d_out, int out_size, void* d_ws, size_t ws_size,
                              hipStream_t stream) {
    const float* z  = (const float*)d_in[0];
    const float* cb = (const float*)d_in[1];
    float* out  = (float*)d_out;
    float* idxf = out + 4194304;
    float* loss = out + 4210688;
    // scratch inside the z_q region of d_out (fully overwritten at the end):
    char* ob = (char*)d_out;
    short* zh    = (short*)ob;                    // [0 .. 8MB)   bf16 z [p][k]
    short* eh    = (short*)(ob + 8388608);        // [8 .. 12MB)  bf16 codebook
    u32*   best4 = (u32*)(ob + 12582912);         // [12 .. 16MB) 16384 x 16 x 4 u32

    char* ws = (char*)d_ws;
    u64*   final_ = (u64*)ws;                // 128 KB @ 0
    float* e2     = (float*)(ws + 131072);   // 32 KB

    hipMemsetAsync(final_, 0xFF, 131072, stream);
    hipMemsetAsync(loss, 0, 4, stream);

    vq_prep<<<2048, 256, 0, stream>>>(cb, eh, e2);
    vq_zh<<<dim3(16, 4, 16), 256, 0, stream>>>(z, zh);
    vq_gemm<<<dim3(NPIX / 128, NE / (NT * 128)), 256, 0, stream>>>(zh, eh, best4);
    vq_exact<<<NPIX / 16, 256, 0, stream>>>(z, cb, e2, best4, final_);
    vq_out_kernel<<<NPIX / 32, 256, 0, stream>>>(z, cb, final_, out, idxf, loss);
}

// Round 23
// 194.263 us; speedup vs baseline: 1.4757x; 1.0193x over previous
//
#include <hip/hip_runtime.h>
#include <float.h>

#define NPIX 16384    // B*H*W pixels
#define NE   8192     // codebook entries
#define KD   256      // channels
#define HW   1024
#define BCHW 262144
#define NT   8        // N-tiles (128 codes) per wg -> wg spans 1024 codes (slice)
#define DELTA 2.5e-4f // rescue window: bf16 err + 2x key quant + margin
#define KMASK 0xFFFFE000u

typedef __attribute__((ext_vector_type(8))) short short8;
typedef __attribute__((ext_vector_type(4))) short short4v;
typedef __attribute__((ext_vector_type(4))) float f32x4;
typedef __attribute__((ext_vector_type(4))) unsigned int u32x4;
typedef unsigned long long u64;
typedef unsigned int u32;

__device__ __forceinline__ u32 fkey(float f) {
    u32 u = __float_as_uint(f);
    return u ^ ((u >> 31) ? 0xFFFFFFFFu : 0x80000000u);
}
__device__ __forceinline__ short bf16rne(float f) {
    u32 u = __float_as_uint(f);
    u += 0x7FFFu + ((u >> 16) & 1u);
    return (short)(u >> 16);
}
__device__ __forceinline__ float kval(u32 pk) {   // packed key -> quantized value
    return __uint_as_float(pk & KMASK);
}

#define GLDS(gp, lp) __builtin_amdgcn_global_load_lds( \
    (const __attribute__((address_space(1))) void*)(gp), \
    (__attribute__((address_space(3))) void*)(lp), 16, 0, 0)

// ---------------------------------------------------------------------------
// prep: codebook -> bf16 AND e2[n] = ||e_n||^2. One wave per row.
// ---------------------------------------------------------------------------
__global__ void vq_prep(const float* __restrict__ cb, short* __restrict__ eh,
                        float* __restrict__ e2) {
    const int row  = (blockIdx.x * 256 + threadIdx.x) >> 6;
    const int lane = threadIdx.x & 63;
    const f32x4 v = *(const f32x4*)(cb + (size_t)row * KD + lane * 4);
    short4v h;
    h[0] = bf16rne(v[0]); h[1] = bf16rne(v[1]);
    h[2] = bf16rne(v[2]); h[3] = bf16rne(v[3]);
    *(short4v*)(eh + (size_t)row * KD + lane * 4) = h;
    float s = v[0]*v[0] + v[1]*v[1] + v[2]*v[2] + v[3]*v[3];
    #pragma unroll
    for (int m = 1; m < 64; m <<= 1) s += __shfl_xor(s, m);
    if (lane == 0) e2[row] = s;
}

// ---------------------------------------------------------------------------
// z [b][k][hw] fp32 -> zh [p][k] bf16 (transpose via LDS)
// ---------------------------------------------------------------------------
__global__ void vq_zh(const float* __restrict__ z, short* __restrict__ zh) {
    __shared__ float ts[64][65];
    const int b   = blockIdx.z;
    const int k0  = blockIdx.y * 64;
    const int hw0 = blockIdx.x * 64;
    const int tid = threadIdx.x;
    const int pl  = tid & 63, kk = tid >> 6;
    #pragma unroll
    for (int i = 0; i < 16; ++i) {
        const int k = kk + 4 * i;
        ts[k][pl] = z[b * BCHW + (k0 + k) * HW + hw0 + pl];
    }
    __syncthreads();
    const int tx = tid & 15, ty = tid >> 4;
    #pragma unroll
    for (int j = 0; j < 4; ++j) {
        const int p = ty + 16 * j;
        short4v v;
        #pragma unroll
        for (int q = 0; q < 4; ++q) v[q] = bf16rne(ts[tx * 4 + q][p]);
        *(short4v*)(zh + (size_t)(b * HW + hw0 + p) * KD + k0 + tx * 4) = v;
    }
}

// ---------------------------------------------------------------------------
// Fused GEMM + per-(pixel, HALF-slice) top-4 tracking.
// R23: BARRIER-FREE K-loop via WAVE-PRIVATE B staging. Each wave stages
// only its own wn-half (64 rows) into a private 4-buffer LDS region
// (4 KB x 4 = 16 KB/wave, 64 KB/wg) -> no cross-wave data sharing -> no
// s_barrier anywhere in the loop. Waves free-run; the HW scheduler
// interleaves their LDS / MFMA phases (vs R18's lockstep bursts).
// Waves sharing a wn duplicate B loads (2x GLDS, L2-absorbed).
// A cached in registers once per wg (R18). vmcnt counted per wave.
// ---------------------------------------------------------------------------
__global__ __launch_bounds__(256, 2) void vq_gemm(
    const short* __restrict__ zh, const short* __restrict__ eh,
    u32* __restrict__ best4)
{
    __shared__ short Bs[4][4][2048];  // [wave][buf][64 rows x 32 k] = 64 KB

    const int tid  = threadIdx.x;
    const int lane = tid & 63;
    const int w    = tid >> 6;
    const int wm   = w >> 1, wn = w & 1;
    const int p0   = blockIdx.x * 128;
    const int nb0  = blockIdx.y * (NT * 128);

    const int sr = lane >> 2;                  // row within 16-row GLDS block
    const int ss = (lane & 3) ^ ((sr >> 1) & 3);
    const int q   = lane >> 4;
    const int rsw = ((lane & 15) >> 1) & 3;

    u32 b1[4][4], b2[4][4];
    #pragma unroll
    for (int m = 0; m < 4; ++m)
        #pragma unroll
        for (int r = 0; r < 4; ++r) { b1[m][r] = 0xFFFFFFFFu; b2[m][r] = 0xFFFFFFFFu; }

    // ---- A-fragments: direct global -> register, once per wg ----
    short8 afr[4][8];
    #pragma unroll
    for (int m = 0; m < 4; ++m) {
        const size_t rowb = (size_t)(p0 + wm * 64 + m * 16 + (lane & 15)) * KD;
        #pragma unroll
        for (int ks = 0; ks < 8; ++ks)
            afr[m][ks] = *(const short8*)(zh + rowb + ks * 32 + q * 8);
    }
    // drain A loads so the loop's counted vmcnt tracks ONLY B stages
    asm volatile("s_waitcnt vmcnt(0)" ::: "memory");

    // stage this wave's 64 B rows for tile (nt_, t_) into private buf_
    // (4 GLDS x 16 rows; linear dest, pre-swizzled source slot)
    #define STAGEB(nt_, t_, buf_) do {                                         \
        const int k0_ = (t_) * 32;                                             \
        const int n0_ = nb0 + (nt_) * 128 + wn * 64;                           \
        _Pragma("unroll")                                                      \
        for (int i_ = 0; i_ < 4; ++i_) {                                       \
            GLDS(eh + (size_t)(n0_ + i_ * 16 + sr) * KD + k0_ + ss * 8,        \
                 &Bs[w][buf_][i_ * 512]);                                      \
        }                                                                      \
    } while (0)

    f32x4 acc[4][4];

    STAGEB(0, 0, 0);
    STAGEB(0, 1, 1);

    #pragma unroll 1
    for (int nt = 0; nt < NT; ++nt) {
        const bool lastnt = (nt == NT - 1);
        #pragma unroll
        for (int t = 0; t < 8; ++t) {
            // own tile-(nt,t) 4 loads landed; tile-(t+1)'s 4 stay in flight
            if (lastnt && t == 7) asm volatile("s_waitcnt vmcnt(0)" ::: "memory");
            else                  asm volatile("s_waitcnt vmcnt(4)" ::: "memory");
            __builtin_amdgcn_sched_barrier(0);
            // NO s_barrier: buffer is wave-private.

            if (t < 6)        { STAGEB(nt, t + 2, (t + 2) & 3); }
            else if (!lastnt) { STAGEB(nt + 1, t - 6, (t - 6) & 3); }

            if (t == 0) {
                #pragma unroll
                for (int m = 0; m < 4; ++m)
                    #pragma unroll
                    for (int nf = 0; nf < 4; ++nf)
                        acc[m][nf] = (f32x4){0.f, 0.f, 0.f, 0.f};
            }

            short8 bfv[4];
            #pragma unroll
            for (int nf = 0; nf < 4; ++nf) {
                const int row = nf * 16 + (lane & 15);      // within own half
                bfv[nf] = *(const short8*)&Bs[w][t & 3][row * 32 + ((q ^ rsw) * 8)];
            }
            #pragma unroll
            for (int m = 0; m < 4; ++m)
                #pragma unroll
                for (int nf = 0; nf < 4; ++nf)
                    acc[m][nf] = __builtin_amdgcn_mfma_f32_16x16x32_bf16(
                        afr[m][t], bfv[nf], acc[m][nf], 0, 0, 0);

            if (t == 7) {
                // ---- register-only best-2 merge (no shfl, no globals) ----
                const u32 nbase = (u32)(nb0 + nt * 128 + wn * 64 + (lane & 15));
                #pragma unroll
                for (int m = 0; m < 4; ++m) {
                    #pragma unroll
                    for (int r = 0; r < 4; ++r) {
                        u32 pk0 = (__float_as_uint(0.0625f - acc[m][0][r]) & KMASK) | (nbase);
                        u32 pk1 = (__float_as_uint(0.0625f - acc[m][1][r]) & KMASK) | (nbase + 16u);
                        u32 pk2 = (__float_as_uint(0.0625f - acc[m][2][r]) & KMASK) | (nbase + 32u);
                        u32 pk3 = (__float_as_uint(0.0625f - acc[m][3][r]) & KMASK) | (nbase + 48u);
                        const u32 lo01 = min(pk0, pk1), hi01 = max(pk0, pk1);
                        const u32 lo23 = min(pk2, pk3), hi23 = max(pk2, pk3);
                        const u32 m1 = min(lo01, lo23);
                        const u32 m2 = min(max(lo01, lo23), min(hi01, hi23));
                        const u32 nb1 = min(b1[m][r], m1);
                        const u32 nb2 = min(max(b1[m][r], m1), min(b2[m][r], m2));
                        b1[m][r] = nb1; b2[m][r] = nb2;
                    }
                }
            }
        }
    }
    #undef STAGEB

    // ---- wg-end: top-4 of this wave's 32-key lane-union per pixel ----
    const int g = lane >> 4;
    const int hs = blockIdx.y * 2 + wn;          // half-slice: single writer
    #pragma unroll
    for (int m = 0; m < 4; ++m) {
        #pragma unroll
        for (int r = 0; r < 4; ++r) {
            u32 a = b1[m][r], b = b2[m][r];
            u32 o[4];
            #pragma unroll
            for (int j = 0; j < 4; ++j) {
                u32 mm = a;
                #pragma unroll
                for (int msk = 1; msk < 16; msk <<= 1)
                    mm = min(mm, (u32)__shfl_xor((int)mm, msk));
                o[j] = mm;
                if (a == mm) { a = b; b = 0xFFFFFFFFu; }
            }
            if ((lane & 15) == 0) {
                const int prow = p0 + wm * 64 + m * 16 + g * 4 + r;
                u32x4 ov; ov[0] = o[0]; ov[1] = o[1]; ov[2] = o[2]; ov[3] = o[3];
                *(u32x4*)&best4[((size_t)prow * 16 + hs) * 4] = ov;
            }
        }
    }
}

// ---------------------------------------------------------------------------
// exact (parallel): one wg per 16 pixels, 256 threads. Unchanged from R15.
// ---------------------------------------------------------------------------
__global__ __launch_bounds__(256) void vq_exact(
    const float* __restrict__ z, const float* __restrict__ cb,
    const float* __restrict__ e2, const u32* __restrict__ best4,
    u64* __restrict__ final_)
{
    __shared__ float zb[16][260];
    __shared__ u32 work[1024];     // (pix<<13) | n
    __shared__ u32 scans[256];     // (pix<<4) | hsx
    __shared__ int nwork, nscan;

    const int tid = threadIdx.x;
    const int g0  = blockIdx.x * 16;
    const int bb  = g0 >> 10, hw0 = g0 & 1023;
    const int pix = tid >> 4;
    const int hsx = tid & 15;

    if (tid == 0) { nwork = 0; nscan = 0; }
    __syncthreads();

    // Phase A ------------------------------------------------------------
    const u32x4 kv = *(const u32x4*)&best4[((size_t)(g0 + pix) * 16 + hsx) * 4];
    const u32 lmin = min(min(kv[0], kv[1]), min(kv[2], kv[3]));
    u32 mn = lmin;
    #pragma unroll
    for (int m = 1; m < 16; m <<= 1) mn = min(mn, (u32)__shfl_xor((int)mn, m));
    const float thr = kval(mn) + DELTA;
    const int c4 = (kval(kv[0]) <= thr ? 1 : 0) + (kval(kv[1]) <= thr ? 1 : 0)
                 + (kval(kv[2]) <= thr ? 1 : 0) + (kval(kv[3]) <= thr ? 1 : 0);
    int cnt = c4;
    #pragma unroll
    for (int m = 1; m < 16; m <<= 1) cnt += __shfl_xor(cnt, m);
    const int susp = (c4 == 4) ? 1 : 0;
    int anysusp = susp;
    #pragma unroll
    for (int m = 1; m < 16; m <<= 1) anysusp += __shfl_xor(anysusp, m);

    if (cnt == 1 && anysusp == 0) {
        if (lmin == mn) final_[g0 + pix] = (u64)(mn & 8191u);
    } else {
        if (c4 > 0) {
            const int base = atomicAdd(&nwork, c4);
            int k = 0;
            #pragma unroll
            for (int j = 0; j < 4; ++j)
                if (kval(kv[j]) <= thr)
                    work[base + (k++)] = ((u32)pix << 13) | (kv[j] & 8191u);
        }
        if (susp) scans[atomicAdd(&nscan, 1)] = ((u32)pix << 4) | (u32)hsx;
    }
    __syncthreads();
    const int nw = nwork, ns = nscan;
    if (nw == 0 && ns == 0) return;

    // Phase B: stage the 16-pixel z block coalesced ------------------------
    #pragma unroll
    for (int i = 0; i < 16; ++i) {
        const int idx = i * 256 + tid;
        const int c = idx >> 4, px = idx & 15;
        zb[px][c] = z[(size_t)bb * BCHW + (size_t)c * HW + hw0 + px];
    }
    __syncthreads();

    // Phase C: one thread per passer candidate ----------------------------
    for (int i = tid; i < nw; i += 256) {
        const u32 e = work[i];
        const int px = (int)(e >> 13), n = (int)(e & 8191u);
        const float* er = cb + (size_t)n * KD;
        float acc = 0.f;
        #pragma unroll 4
        for (int k = 0; k < KD; k += 4) {
            const f32x4 zv = *(const f32x4*)&zb[px][k];
            const f32x4 ev = *(const f32x4*)(er + k);
            acc += zv[0]*ev[0] + zv[1]*ev[1] + zv[2]*ev[2] + zv[3]*ev[3];
        }
        const float s = 0.5f * e2[n] - acc;
        atomicMin(&final_[g0 + px], ((u64)fkey(s) << 32) | (u32)n);
    }

    // Phase D: suspect half-slice scans (rare) ----------------------------
    for (int si = 0; si < ns; ++si) {
        const u32 e = scans[si];
        const int px = (int)(e >> 4), hx = (int)(e & 15u);
        u64 bku = ~0ULL;
        #pragma unroll
        for (int h = 0; h < 2; ++h) {
            const int ci = tid + h * 256;
            const int n = (hx >> 1) * 1024 + (ci >> 6) * 128
                        + (hx & 1) * 64 + (ci & 63);
            const float* er = cb + (size_t)n * KD;
            float acc = 0.f;
            #pragma unroll 4
            for (int k = 0; k < KD; k += 4) {
                const f32x4 zv = *(const f32x4*)&zb[px][k];
                const f32x4 ev = *(const f32x4*)(er + k);
                acc += zv[0]*ev[0] + zv[1]*ev[1] + zv[2]*ev[2] + zv[3]*ev[3];
            }
            const float s = 0.5f * e2[n] - acc;
            const u64 pk = ((u64)fkey(s) << 32) | (u32)n;
            bku = min(bku, pk);
        }
        #pragma unroll
        for (int m = 1; m < 64; m <<= 1) {
            const u64 o = (u64)__shfl_xor((long long)bku, m);
            bku = min(bku, o);
        }
        if ((tid & 63) == 0) atomicMin(&final_[g0 + px], bku);
    }
}

// ---------------------------------------------------------------------------
// Output kernel, tile-transposed.
// ---------------------------------------------------------------------------
__global__ __launch_bounds__(256) void vq_out_kernel(
    const float* __restrict__ z, const float* __restrict__ cb,
    const u64* __restrict__ final_, float* __restrict__ out,
    float* __restrict__ idxf, float* __restrict__ loss)
{
    __shared__ float zq[32][257];
    __shared__ int   nidx[32];

    const int tid = threadIdx.x;
    const int p0  = blockIdx.x * 32;
    const int bb  = p0 >> 10;
    const int hw0 = p0 & 1023;

    if (tid < 32) {
        const int n = (int)((u32)final_[p0 + tid] & 8191u);
        nidx[tid] = n;
        idxf[p0 + tid] = (float)n;
    }
    __syncthreads();

    {
        const int r = tid >> 3, i = tid & 7;
        const float* src = cb + (size_t)nidx[r] * KD;
        #pragma unroll
        for (int j = 0; j < 8; ++j) {
            const int col = i * 4 + j * 32;
            const f32x4 v = *(const f32x4*)(src + col);
            zq[r][col + 0] = v[0]; zq[r][col + 1] = v[1];
            zq[r][col + 2] = v[2]; zq[r][col + 3] = v[3];
        }
    }
    __syncthreads();

    const int p4 = (tid & 7) * 4;
    const int cg = tid >> 3;
    float ls = 0.f;
    #pragma unroll
    for (int ii = 0; ii < 8; ++ii) {
        const int c = cg + 32 * ii;
        const size_t e = (size_t)bb * BCHW + (size_t)c * HW + hw0 + p4;
        const f32x4 zv = *(const f32x4*)(z + e);
        f32x4 v;
        v[0] = zq[p4 + 0][c]; v[1] = zq[p4 + 1][c];
        v[2] = zq[p4 + 2][c]; v[3] = zq[p4 + 3][c];
        *(f32x4*)(out + e) = v;
        const float d0 = v[0] - zv[0], d1 = v[1] - zv[1];
        const float d2 = v[2] - zv[2], d3 = v[3] - zv[3];
        ls += d0 * d0 + d1 * d1 + d2 * d2 + d3 * d3;
    }
    #pragma unroll
    for (int m = 1; m < 64; m <<= 1) ls += __shfl_xor(ls, m);
    if ((tid & 63) == 0) atomicAdd(loss, ls * (1.25f / 4194304.f));
}

// ---------------------------------------------------------------------------
extern "C" void kernel_launch(void* const* d_in, const int* in_sizes, int n_in,
                              void* d_out, int out_size, void* d_ws, size_t ws_size,
                              hipStream_t stream) {
    const float* z  = (const float*)d_in[0];
    const float* cb = (const float*)d_in[1];
    float* out  = (float*)d_out;
    float* idxf = out + 4194304;
    float* loss = out + 4210688;
    // scratch inside the z_q region of d_out (fully overwritten at the end):
    char* ob = (char*)d_out;
    short* zh    = (short*)ob;                    // [0 .. 8MB)   bf16 z [p][k]
    short* eh    = (short*)(ob + 8388608);        // [8 .. 12MB)  bf16 codebook
    u32*   best4 = (u32*)(ob + 12582912);         // [12 .. 16MB) 16384 x 16 x 4 u32

    char* ws = (char*)d_ws;
    u64*   final_ = (u64*)ws;                // 128 KB @ 0
    float* e2     = (float*)(ws + 131072);   // 32 KB

    hipMemsetAsync(final_, 0xFF, 131072, stream);
    hipMemsetAsync(loss, 0, 4, stream);

    vq_prep<<<2048, 256, 0, stream>>>(cb, eh, e2);
    vq_zh<<<dim3(16, 4, 16), 256, 0, stream>>>(z, zh);
    vq_gemm<<<dim3(NPIX / 128, NE / (NT * 128)), 256, 0, stream>>>(zh, eh, best4);
    vq_exact<<<NPIX / 16, 256, 0, stream>>>(z, cb, e2, best4, final_);
    vq_out_kernel<<<NPIX / 32, 256, 0, stream>>>(z, cb, final_, out, idxf, loss);
}

// Round 24
// 191.585 us; speedup vs baseline: 1.4964x; 1.0140x over previous
//
#include <hip/hip_runtime.h>
#include <float.h>

#define NPIX 16384    // B*H*W pixels
#define NE   8192     // codebook entries
#define KD   256      // channels
#define HW   1024
#define BCHW 262144
#define NT   8        // N-tiles (128 codes) per wg -> wg spans 1024 codes (slice)
#define DELTA 2.5e-4f // rescue window: bf16 err + 2x key quant + margin
#define KMASK 0xFFFFE000u

typedef __attribute__((ext_vector_type(8))) short short8;
typedef __attribute__((ext_vector_type(4))) short short4v;
typedef __attribute__((ext_vector_type(4))) float f32x4;
typedef __attribute__((ext_vector_type(4))) unsigned int u32x4;
typedef unsigned long long u64;
typedef unsigned int u32;

__device__ __forceinline__ u32 fkey(float f) {
    u32 u = __float_as_uint(f);
    return u ^ ((u >> 31) ? 0xFFFFFFFFu : 0x80000000u);
}
__device__ __forceinline__ short bf16rne(float f) {
    u32 u = __float_as_uint(f);
    u += 0x7FFFu + ((u >> 16) & 1u);
    return (short)(u >> 16);
}
__device__ __forceinline__ float kval(u32 pk) {   // packed key -> quantized value
    return __uint_as_float(pk & KMASK);
}

#define GLDS(gp, lp) __builtin_amdgcn_global_load_lds( \
    (const __attribute__((address_space(1))) void*)(gp), \
    (__attribute__((address_space(3))) void*)(lp), 16, 0, 0)

// ---------------------------------------------------------------------------
// prep: codebook -> bf16 AND e2[n] = ||e_n||^2. One wave per row.
// ---------------------------------------------------------------------------
__global__ void vq_prep(const float* __restrict__ cb, short* __restrict__ eh,
                        float* __restrict__ e2) {
    const int row  = (blockIdx.x * 256 + threadIdx.x) >> 6;
    const int lane = threadIdx.x & 63;
    const f32x4 v = *(const f32x4*)(cb + (size_t)row * KD + lane * 4);
    short4v h;
    h[0] = bf16rne(v[0]); h[1] = bf16rne(v[1]);
    h[2] = bf16rne(v[2]); h[3] = bf16rne(v[3]);
    *(short4v*)(eh + (size_t)row * KD + lane * 4) = h;
    float s = v[0]*v[0] + v[1]*v[1] + v[2]*v[2] + v[3]*v[3];
    #pragma unroll
    for (int m = 1; m < 64; m <<= 1) s += __shfl_xor(s, m);
    if (lane == 0) e2[row] = s;
}

// ---------------------------------------------------------------------------
// z [b][k][hw] fp32 -> zh [p][k] bf16 (transpose via LDS)
// ---------------------------------------------------------------------------
__global__ void vq_zh(const float* __restrict__ z, short* __restrict__ zh) {
    __shared__ float ts[64][65];
    const int b   = blockIdx.z;
    const int k0  = blockIdx.y * 64;
    const int hw0 = blockIdx.x * 64;
    const int tid = threadIdx.x;
    const int pl  = tid & 63, kk = tid >> 6;
    #pragma unroll
    for (int i = 0; i < 16; ++i) {
        const int k = kk + 4 * i;
        ts[k][pl] = z[b * BCHW + (k0 + k) * HW + hw0 + pl];
    }
    __syncthreads();
    const int tx = tid & 15, ty = tid >> 4;
    #pragma unroll
    for (int j = 0; j < 4; ++j) {
        const int p = ty + 16 * j;
        short4v v;
        #pragma unroll
        for (int q = 0; q < 4; ++q) v[q] = bf16rne(ts[tx * 4 + q][p]);
        *(short4v*)(zh + (size_t)(b * HW + hw0 + p) * KD + k0 + tx * 4) = v;
    }
}

// ---------------------------------------------------------------------------
// Fused GEMM + per-(pixel, HALF-slice) top-4 tracking.
// R24: SMALL WAVE-TILE for 4 waves/SIMD. 512 threads = 8 waves (4M x 2N);
// per-wave tile 32 pixels x 64 codes (2x4 frags) -> register need ~112
// (acc 32 AGPR + afr 32 + track 16 + frags/temps) fits the 128-reg budget
// of launch_bounds(512,2) = 4 waves/SIMD, 2x the occupancy of R18.
// Schedule identical to R17/R18 (4 static B buffers, 1 barrier/step,
// counted vmcnt, pre-swizzled GLDS source): hazard distances unchanged.
// Per-wave GLDS = 1/tile -> loop wait is vmcnt(1).
// ---------------------------------------------------------------------------
__global__ __launch_bounds__(512, 2) void vq_gemm(
    const short* __restrict__ zh, const short* __restrict__ eh,
    u32* __restrict__ best4)
{
    __shared__ short Bs[4][4096];   // [buf][128 rows x 32 k]  (32 KB)

    const int tid  = threadIdx.x;
    const int lane = tid & 63;
    const int w    = tid >> 6;          // 0..7
    const int wm   = w >> 1, wn = w & 1;
    const int lr   = lane & 15;
    const int p0   = blockIdx.x * 128;
    const int nb0  = blockIdx.y * (NT * 128);

    const int sr = lane >> 2;           // 0..15 row in wave's 16-row block
    const int ss = (lane & 3) ^ ((sr >> 1) & 3);
    const int q   = lane >> 4;
    const int rsw = (lr >> 1) & 3;

    u32 b1[2][4], b2[2][4];
    #pragma unroll
    for (int m = 0; m < 2; ++m)
        #pragma unroll
        for (int r = 0; r < 4; ++r) { b1[m][r] = 0xFFFFFFFFu; b2[m][r] = 0xFFFFFFFFu; }

    // ---- A-fragments: direct global -> register, once per wg ----
    // wave covers pixels p0 + wm*32 + m*16 + lr, m in {0,1}
    short8 afr[2][8];
    #pragma unroll
    for (int m = 0; m < 2; ++m) {
        const size_t rowb = (size_t)(p0 + wm * 32 + m * 16 + lr) * KD;
        #pragma unroll
        for (int ks = 0; ks < 8; ++ks)
            afr[m][ks] = *(const short8*)(zh + rowb + ks * 32 + q * 8);
    }
    // drain A loads so the loop's counted vmcnt tracks ONLY B stages
    asm volatile("s_waitcnt vmcnt(0)" ::: "memory");

    // stage B tile (nt_, t_): each of 8 waves stages its own 16 rows
    #define STAGEB(nt_, t_, buf_) do {                                         \
        const int k0_ = (t_) * 32;                                             \
        const int n0_ = nb0 + (nt_) * 128;                                     \
        GLDS(eh + (size_t)(n0_ + w * 16 + sr) * KD + k0_ + ss * 8,             \
             &Bs[buf_][w * 512]);                                              \
    } while (0)

    f32x4 acc[2][4];

    STAGEB(0, 0, 0);
    STAGEB(0, 1, 1);

    #pragma unroll 1
    for (int nt = 0; nt < NT; ++nt) {
        const bool lastnt = (nt == NT - 1);
        #pragma unroll
        for (int t = 0; t < 8; ++t) {
            // own tile-(nt,t) load landed; the 1 newer stays in flight
            if (lastnt && t == 7) asm volatile("s_waitcnt vmcnt(0)" ::: "memory");
            else                  asm volatile("s_waitcnt vmcnt(1)" ::: "memory");
            __builtin_amdgcn_sched_barrier(0);
            __builtin_amdgcn_s_barrier();   // tile (nt,t) visible to all waves

            if (t < 6)        { STAGEB(nt, t + 2, (t + 2) & 3); }
            else if (!lastnt) { STAGEB(nt + 1, t - 6, (t - 6) & 3); }

            if (t == 0) {
                #pragma unroll
                for (int m = 0; m < 2; ++m)
                    #pragma unroll
                    for (int nf = 0; nf < 4; ++nf)
                        acc[m][nf] = (f32x4){0.f, 0.f, 0.f, 0.f};
            }

            short8 bfv[4];
            #pragma unroll
            for (int nf = 0; nf < 4; ++nf) {
                const int row = wn * 64 + nf * 16 + lr;
                bfv[nf] = *(const short8*)&Bs[t & 3][row * 32 + ((q ^ rsw) * 8)];
            }
            #pragma unroll
            for (int m = 0; m < 2; ++m)
                #pragma unroll
                for (int nf = 0; nf < 4; ++nf)
                    acc[m][nf] = __builtin_amdgcn_mfma_f32_16x16x32_bf16(
                        afr[m][t], bfv[nf], acc[m][nf], 0, 0, 0);

            if (t == 7) {
                // ---- register-only best-2 merge (no shfl, no globals) ----
                const u32 nbase = (u32)(nb0 + nt * 128 + wn * 64 + lr);
                #pragma unroll
                for (int m = 0; m < 2; ++m) {
                    #pragma unroll
                    for (int r = 0; r < 4; ++r) {
                        u32 pk0 = (__float_as_uint(0.0625f - acc[m][0][r]) & KMASK) | (nbase);
                        u32 pk1 = (__float_as_uint(0.0625f - acc[m][1][r]) & KMASK) | (nbase + 16u);
                        u32 pk2 = (__float_as_uint(0.0625f - acc[m][2][r]) & KMASK) | (nbase + 32u);
                        u32 pk3 = (__float_as_uint(0.0625f - acc[m][3][r]) & KMASK) | (nbase + 48u);
                        const u32 lo01 = min(pk0, pk1), hi01 = max(pk0, pk1);
                        const u32 lo23 = min(pk2, pk3), hi23 = max(pk2, pk3);
                        const u32 m1 = min(lo01, lo23);
                        const u32 m2 = min(max(lo01, lo23), min(hi01, hi23));
                        const u32 nb1 = min(b1[m][r], m1);
                        const u32 nb2 = min(max(b1[m][r], m1), min(b2[m][r], m2));
                        b1[m][r] = nb1; b2[m][r] = nb2;
                    }
                }
            }
        }
    }
    #undef STAGEB

    // ---- wg-end: top-4 of this wave's 16-key lane-union per pixel ----
    // (per pixel: 16 lanes x best-2 = 32 tracked keys, as before)
    const int g = lane >> 4;
    const int hs = blockIdx.y * 2 + wn;          // half-slice: single writer
    #pragma unroll
    for (int m = 0; m < 2; ++m) {
        #pragma unroll
        for (int r = 0; r < 4; ++r) {
            u32 a = b1[m][r], b = b2[m][r];
            u32 o[4];
            #pragma unroll
            for (int j = 0; j < 4; ++j) {
                u32 mm = a;
                #pragma unroll
                for (int msk = 1; msk < 16; msk <<= 1)
                    mm = min(mm, (u32)__shfl_xor((int)mm, msk));
                o[j] = mm;
                if (a == mm) { a = b; b = 0xFFFFFFFFu; }
            }
            if (lr == 0) {
                const int prow = p0 + wm * 32 + m * 16 + g * 4 + r;
                u32x4 ov; ov[0] = o[0]; ov[1] = o[1]; ov[2] = o[2]; ov[3] = o[3];
                *(u32x4*)&best4[((size_t)prow * 16 + hs) * 4] = ov;
            }
        }
    }
}

// ---------------------------------------------------------------------------
// exact (parallel): one wg per 16 pixels, 256 threads. Unchanged from R15.
// ---------------------------------------------------------------------------
__global__ __launch_bounds__(256) void vq_exact(
    const float* __restrict__ z, const float* __restrict__ cb,
    const float* __restrict__ e2, const u32* __restrict__ best4,
    u64* __restrict__ final_)
{
    __shared__ float zb[16][260];
    __shared__ u32 work[1024];     // (pix<<13) | n
    __shared__ u32 scans[256];     // (pix<<4) | hsx
    __shared__ int nwork, nscan;

    const int tid = threadIdx.x;
    const int g0  = blockIdx.x * 16;
    const int bb  = g0 >> 10, hw0 = g0 & 1023;
    const int pix = tid >> 4;
    const int hsx = tid & 15;

    if (tid == 0) { nwork = 0; nscan = 0; }
    __syncthreads();

    // Phase A ------------------------------------------------------------
    const u32x4 kv = *(const u32x4*)&best4[((size_t)(g0 + pix) * 16 + hsx) * 4];
    const u32 lmin = min(min(kv[0], kv[1]), min(kv[2], kv[3]));
    u32 mn = lmin;
    #pragma unroll
    for (int m = 1; m < 16; m <<= 1) mn = min(mn, (u32)__shfl_xor((int)mn, m));
    const float thr = kval(mn) + DELTA;
    const int c4 = (kval(kv[0]) <= thr ? 1 : 0) + (kval(kv[1]) <= thr ? 1 : 0)
                 + (kval(kv[2]) <= thr ? 1 : 0) + (kval(kv[3]) <= thr ? 1 : 0);
    int cnt = c4;
    #pragma unroll
    for (int m = 1; m < 16; m <<= 1) cnt += __shfl_xor(cnt, m);
    const int susp = (c4 == 4) ? 1 : 0;
    int anysusp = susp;
    #pragma unroll
    for (int m = 1; m < 16; m <<= 1) anysusp += __shfl_xor(anysusp, m);

    if (cnt == 1 && anysusp == 0) {
        if (lmin == mn) final_[g0 + pix] = (u64)(mn & 8191u);
    } else {
        if (c4 > 0) {
            const int base = atomicAdd(&nwork, c4);
            int k = 0;
            #pragma unroll
            for (int j = 0; j < 4; ++j)
                if (kval(kv[j]) <= thr)
                    work[base + (k++)] = ((u32)pix << 13) | (kv[j] & 8191u);
        }
        if (susp) scans[atomicAdd(&nscan, 1)] = ((u32)pix << 4) | (u32)hsx;
    }
    __syncthreads();
    const int nw = nwork, ns = nscan;
    if (nw == 0 && ns == 0) return;

    // Phase B: stage the 16-pixel z block coalesced ------------------------
    #pragma unroll
    for (int i = 0; i < 16; ++i) {
        const int idx = i * 256 + tid;
        const int c = idx >> 4, px = idx & 15;
        zb[px][c] = z[(size_t)bb * BCHW + (size_t)c * HW + hw0 + px];
    }
    __syncthreads();

    // Phase C: one thread per passer candidate ----------------------------
    for (int i = tid; i < nw; i += 256) {
        const u32 e = work[i];
        const int px = (int)(e >> 13), n = (int)(e & 8191u);
        const float* er = cb + (size_t)n * KD;
        float acc = 0.f;
        #pragma unroll 4
        for (int k = 0; k < KD; k += 4) {
            const f32x4 zv = *(const f32x4*)&zb[px][k];
            const f32x4 ev = *(const f32x4*)(er + k);
            acc += zv[0]*ev[0] + zv[1]*ev[1] + zv[2]*ev[2] + zv[3]*ev[3];
        }
        const float s = 0.5f * e2[n] - acc;
        atomicMin(&final_[g0 + px], ((u64)fkey(s) << 32) | (u32)n);
    }

    // Phase D: suspect half-slice scans (rare) ----------------------------
    for (int si = 0; si < ns; ++si) {
        const u32 e = scans[si];
        const int px = (int)(e >> 4), hx = (int)(e & 15u);
        u64 bku = ~0ULL;
        #pragma unroll
        for (int h = 0; h < 2; ++h) {
            const int ci = tid + h * 256;
            const int n = (hx >> 1) * 1024 + (ci >> 6) * 128
                        + (hx & 1) * 64 + (ci & 63);
            const float* er = cb + (size_t)n * KD;
            float acc = 0.f;
            #pragma unroll 4
            for (int k = 0; k < KD; k += 4) {
                const f32x4 zv = *(const f32x4*)&zb[px][k];
                const f32x4 ev = *(const f32x4*)(er + k);
                acc += zv[0]*ev[0] + zv[1]*ev[1] + zv[2]*ev[2] + zv[3]*ev[3];
            }
            const float s = 0.5f * e2[n] - acc;
            const u64 pk = ((u64)fkey(s) << 32) | (u32)n;
            bku = min(bku, pk);
        }
        #pragma unroll
        for (int m = 1; m < 64; m <<= 1) {
            const u64 o = (u64)__shfl_xor((long long)bku, m);
            bku = min(bku, o);
        }
        if ((tid & 63) == 0) atomicMin(&final_[g0 + px], bku);
    }
}

// ---------------------------------------------------------------------------
// Output kernel, tile-transposed.
// ---------------------------------------------------------------------------
__global__ __launch_bounds__(256) void vq_out_kernel(
    const float* __restrict__ z, const float* __restrict__ cb,
    const u64* __restrict__ final_, float* __restrict__ out,
    float* __restrict__ idxf, float* __restrict__ loss)
{
    __shared__ float zq[32][257];
    __shared__ int   nidx[32];

    const int tid = threadIdx.x;
    const int p0  = blockIdx.x * 32;
    const int bb  = p0 >> 10;
    const int hw0 = p0 & 1023;

    if (tid < 32) {
        const int n = (int)((u32)final_[p0 + tid] & 8191u);
        nidx[tid] = n;
        idxf[p0 + tid] = (float)n;
    }
    __syncthreads();

    {
        const int r = tid >> 3, i = tid & 7;
        const float* src = cb + (size_t)nidx[r] * KD;
        #pragma unroll
        for (int j = 0; j < 8; ++j) {
            const int col = i * 4 + j * 32;
            const f32x4 v = *(const f32x4*)(src + col);
            zq[r][col + 0] = v[0]; zq[r][col + 1] = v[1];
            zq[r][col + 2] = v[2]; zq[r][col + 3] = v[3];
        }
    }
    __syncthreads();

    const int p4 = (tid & 7) * 4;
    const int cg = tid >> 3;
    float ls = 0.f;
    #pragma unroll
    for (int ii = 0; ii < 8; ++ii) {
        const int c = cg + 32 * ii;
        const size_t e = (size_t)bb * BCHW + (size_t)c * HW + hw0 + p4;
        const f32x4 zv = *(const f32x4*)(z + e);
        f32x4 v;
        v[0] = zq[p4 + 0][c]; v[1] = zq[p4 + 1][c];
        v[2] = zq[p4 + 2][c]; v[3] = zq[p4 + 3][c];
        *(f32x4*)(out + e) = v;
        const float d0 = v[0] - zv[0], d1 = v[1] - zv[1];
        const float d2 = v[2] - zv[2], d3 = v[3] - zv[3];
        ls += d0 * d0 + d1 * d1 + d2 * d2 + d3 * d3;
    }
    #pragma unroll
    for (int m = 1; m < 64; m <<= 1) ls += __shfl_xor(ls, m);
    if ((tid & 63) == 0) atomicAdd(loss, ls * (1.25f / 4194304.f));
}

// ---------------------------------------------------------------------------
extern "C" void kernel_launch(void* const* d_in, const int* in_sizes, int n_in,
                              void* d_out, int out_size, void* d_ws, size_t ws_size,
                              hipStream_t stream) {
    const float* z  = (const float*)d_in[0];
    const float* cb = (const float*)d_in[1];
    float* out  = (float*)d_out;
    float* idxf = out + 4194304;
    float* loss = out + 4210688;
    // scratch inside the z_q region of d_out (fully overwritten at the end):
    char* ob = (char*)d_out;
    short* zh    = (short*)ob;                    // [0 .. 8MB)   bf16 z [p][k]
    short* eh    = (short*)(ob + 8388608);        // [8 .. 12MB)  bf16 codebook
    u32*   best4 = (u32*)(ob + 12582912);         // [12 .. 16MB) 16384 x 16 x 4 u32

    char* ws = (char*)d_ws;
    u64*   final_ = (u64*)ws;                // 128 KB @ 0
    float* e2     = (float*)(ws + 131072);   // 32 KB

    hipMemsetAsync(final_, 0xFF, 131072, stream);
    hipMemsetAsync(loss, 0, 4, stream);

    vq_prep<<<2048, 256, 0, stream>>>(cb, eh, e2);
    vq_zh<<<dim3(16, 4, 16), 256, 0, stream>>>(z, zh);
    vq_gemm<<<dim3(NPIX / 128, NE / (NT * 128)), 512, 0, stream>>>(zh, eh, best4);
    vq_exact<<<NPIX / 16, 256, 0, stream>>>(z, cb, e2, best4, final_);
    vq_out_kernel<<<NPIX / 32, 256, 0, stream>>>(z, cb, final_, out, idxf, loss);
}

// Round 25
// 179.704 us; speedup vs baseline: 1.5953x; 1.0661x over previous
//
#include <hip/hip_runtime.h>
#include <float.h>

#define NPIX 16384    // B*H*W pixels
#define NE   8192     // codebook entries
#define KD   256      // channels
#define HW   1024
#define BCHW 262144
#define NT   8        // N-tiles (128 codes) per wg -> wg spans 1024 codes (slice)
#define DELTA 2.5e-4f // rescue window: bf16 err + 2x key quant + margin
#define KMASK 0xFFFFE000u

typedef __attribute__((ext_vector_type(8))) short short8;
typedef __attribute__((ext_vector_type(4))) short short4v;
typedef __attribute__((ext_vector_type(4))) float f32x4;
typedef __attribute__((ext_vector_type(4))) unsigned int u32x4;
typedef unsigned long long u64;
typedef unsigned int u32;

__device__ __forceinline__ u32 fkey(float f) {
    u32 u = __float_as_uint(f);
    return u ^ ((u >> 31) ? 0xFFFFFFFFu : 0x80000000u);
}
__device__ __forceinline__ short bf16rne(float f) {
    u32 u = __float_as_uint(f);
    u += 0x7FFFu + ((u >> 16) & 1u);
    return (short)(u >> 16);
}
__device__ __forceinline__ float kval(u32 pk) {   // packed key -> quantized value
    return __uint_as_float(pk & KMASK);
}

#define GLDS(gp, lp) __builtin_amdgcn_global_load_lds( \
    (const __attribute__((address_space(1))) void*)(gp), \
    (__attribute__((address_space(3))) void*)(lp), 16, 0, 0)

// ---------------------------------------------------------------------------
// prep: codebook -> bf16 AND e2[n] = ||e_n||^2. One wave per row.
// ---------------------------------------------------------------------------
__global__ void vq_prep(const float* __restrict__ cb, short* __restrict__ eh,
                        float* __restrict__ e2) {
    const int row  = (blockIdx.x * 256 + threadIdx.x) >> 6;
    const int lane = threadIdx.x & 63;
    const f32x4 v = *(const f32x4*)(cb + (size_t)row * KD + lane * 4);
    short4v h;
    h[0] = bf16rne(v[0]); h[1] = bf16rne(v[1]);
    h[2] = bf16rne(v[2]); h[3] = bf16rne(v[3]);
    *(short4v*)(eh + (size_t)row * KD + lane * 4) = h;
    float s = v[0]*v[0] + v[1]*v[1] + v[2]*v[2] + v[3]*v[3];
    #pragma unroll
    for (int m = 1; m < 64; m <<= 1) s += __shfl_xor(s, m);
    if (lane == 0) e2[row] = s;
}

// ---------------------------------------------------------------------------
// z [b][k][hw] fp32 -> zh [p][k] bf16 (transpose via LDS)
// ---------------------------------------------------------------------------
__global__ void vq_zh(const float* __restrict__ z, short* __restrict__ zh) {
    __shared__ float ts[64][65];
    const int b   = blockIdx.z;
    const int k0  = blockIdx.y * 64;
    const int hw0 = blockIdx.x * 64;
    const int tid = threadIdx.x;
    const int pl  = tid & 63, kk = tid >> 6;
    #pragma unroll
    for (int i = 0; i < 16; ++i) {
        const int k = kk + 4 * i;
        ts[k][pl] = z[b * BCHW + (k0 + k) * HW + hw0 + pl];
    }
    __syncthreads();
    const int tx = tid & 15, ty = tid >> 4;
    #pragma unroll
    for (int j = 0; j < 4; ++j) {
        const int p = ty + 16 * j;
        short4v v;
        #pragma unroll
        for (int q = 0; q < 4; ++q) v[q] = bf16rne(ts[tx * 4 + q][p]);
        *(short4v*)(zh + (size_t)(b * HW + hw0 + p) * KD + k0 + tx * 4) = v;
    }
}

// ---------------------------------------------------------------------------
// Fused GEMM + per-(pixel, HALF-slice) top-4 tracking. (R24, unchanged)
// 512 threads = 8 waves (4M x 2N), per-wave tile 32 px x 64 codes,
// 4 static B buffers, 1 barrier/step, counted vmcnt(1), A in registers.
// ---------------------------------------------------------------------------
__global__ __launch_bounds__(512, 2) void vq_gemm(
    const short* __restrict__ zh, const short* __restrict__ eh,
    u32* __restrict__ best4)
{
    __shared__ short Bs[4][4096];   // [buf][128 rows x 32 k]  (32 KB)

    const int tid  = threadIdx.x;
    const int lane = tid & 63;
    const int w    = tid >> 6;          // 0..7
    const int wm   = w >> 1, wn = w & 1;
    const int lr   = lane & 15;
    const int p0   = blockIdx.x * 128;
    const int nb0  = blockIdx.y * (NT * 128);

    const int sr = lane >> 2;           // 0..15 row in wave's 16-row block
    const int ss = (lane & 3) ^ ((sr >> 1) & 3);
    const int q   = lane >> 4;
    const int rsw = (lr >> 1) & 3;

    u32 b1[2][4], b2[2][4];
    #pragma unroll
    for (int m = 0; m < 2; ++m)
        #pragma unroll
        for (int r = 0; r < 4; ++r) { b1[m][r] = 0xFFFFFFFFu; b2[m][r] = 0xFFFFFFFFu; }

    // ---- A-fragments: direct global -> register, once per wg ----
    short8 afr[2][8];
    #pragma unroll
    for (int m = 0; m < 2; ++m) {
        const size_t rowb = (size_t)(p0 + wm * 32 + m * 16 + lr) * KD;
        #pragma unroll
        for (int ks = 0; ks < 8; ++ks)
            afr[m][ks] = *(const short8*)(zh + rowb + ks * 32 + q * 8);
    }
    asm volatile("s_waitcnt vmcnt(0)" ::: "memory");

    #define STAGEB(nt_, t_, buf_) do {                                         \
        const int k0_ = (t_) * 32;                                             \
        const int n0_ = nb0 + (nt_) * 128;                                     \
        GLDS(eh + (size_t)(n0_ + w * 16 + sr) * KD + k0_ + ss * 8,             \
             &Bs[buf_][w * 512]);                                              \
    } while (0)

    f32x4 acc[2][4];

    STAGEB(0, 0, 0);
    STAGEB(0, 1, 1);

    #pragma unroll 1
    for (int nt = 0; nt < NT; ++nt) {
        const bool lastnt = (nt == NT - 1);
        #pragma unroll
        for (int t = 0; t < 8; ++t) {
            if (lastnt && t == 7) asm volatile("s_waitcnt vmcnt(0)" ::: "memory");
            else                  asm volatile("s_waitcnt vmcnt(1)" ::: "memory");
            __builtin_amdgcn_sched_barrier(0);
            __builtin_amdgcn_s_barrier();

            if (t < 6)        { STAGEB(nt, t + 2, (t + 2) & 3); }
            else if (!lastnt) { STAGEB(nt + 1, t - 6, (t - 6) & 3); }

            if (t == 0) {
                #pragma unroll
                for (int m = 0; m < 2; ++m)
                    #pragma unroll
                    for (int nf = 0; nf < 4; ++nf)
                        acc[m][nf] = (f32x4){0.f, 0.f, 0.f, 0.f};
            }

            short8 bfv[4];
            #pragma unroll
            for (int nf = 0; nf < 4; ++nf) {
                const int row = wn * 64 + nf * 16 + lr;
                bfv[nf] = *(const short8*)&Bs[t & 3][row * 32 + ((q ^ rsw) * 8)];
            }
            #pragma unroll
            for (int m = 0; m < 2; ++m)
                #pragma unroll
                for (int nf = 0; nf < 4; ++nf)
                    acc[m][nf] = __builtin_amdgcn_mfma_f32_16x16x32_bf16(
                        afr[m][t], bfv[nf], acc[m][nf], 0, 0, 0);

            if (t == 7) {
                const u32 nbase = (u32)(nb0 + nt * 128 + wn * 64 + lr);
                #pragma unroll
                for (int m = 0; m < 2; ++m) {
                    #pragma unroll
                    for (int r = 0; r < 4; ++r) {
                        u32 pk0 = (__float_as_uint(0.0625f - acc[m][0][r]) & KMASK) | (nbase);
                        u32 pk1 = (__float_as_uint(0.0625f - acc[m][1][r]) & KMASK) | (nbase + 16u);
                        u32 pk2 = (__float_as_uint(0.0625f - acc[m][2][r]) & KMASK) | (nbase + 32u);
                        u32 pk3 = (__float_as_uint(0.0625f - acc[m][3][r]) & KMASK) | (nbase + 48u);
                        const u32 lo01 = min(pk0, pk1), hi01 = max(pk0, pk1);
                        const u32 lo23 = min(pk2, pk3), hi23 = max(pk2, pk3);
                        const u32 m1 = min(lo01, lo23);
                        const u32 m2 = min(max(lo01, lo23), min(hi01, hi23));
                        const u32 nb1 = min(b1[m][r], m1);
                        const u32 nb2 = min(max(b1[m][r], m1), min(b2[m][r], m2));
                        b1[m][r] = nb1; b2[m][r] = nb2;
                    }
                }
            }
        }
    }
    #undef STAGEB

    // ---- wg-end: top-4 of this wave's lane-union per pixel ----
    const int g = lane >> 4;
    const int hs = blockIdx.y * 2 + wn;          // half-slice: single writer
    #pragma unroll
    for (int m = 0; m < 2; ++m) {
        #pragma unroll
        for (int r = 0; r < 4; ++r) {
            u32 a = b1[m][r], b = b2[m][r];
            u32 o[4];
            #pragma unroll
            for (int j = 0; j < 4; ++j) {
                u32 mm = a;
                #pragma unroll
                for (int msk = 1; msk < 16; msk <<= 1)
                    mm = min(mm, (u32)__shfl_xor((int)mm, msk));
                o[j] = mm;
                if (a == mm) { a = b; b = 0xFFFFFFFFu; }
            }
            if (lr == 0) {
                const int prow = p0 + wm * 32 + m * 16 + g * 4 + r;
                u32x4 ov; ov[0] = o[0]; ov[1] = o[1]; ov[2] = o[2]; ov[3] = o[3];
                *(u32x4*)&best4[((size_t)prow * 16 + hs) * 4] = ov;
            }
        }
    }
}

// ---------------------------------------------------------------------------
// FUSED exact + output: one wg per 32 pixels, 256 threads.
// Phase A: 8 threads/pixel x 2 half-slices each; 8-lane shfl reduce for
//          min/cnt/suspect. Direct-win writes shared sfinal (key 0 wins).
// Stage zb[32][260] (z for these pixels) -- also feeds the loss.
// Phase C: thread-per-passer exact fp32 dot -> LDS atomicMin(sfinal).
// Phase D: suspect half-slice scans, 256 threads x 2 codes, wave-reduce.
// Then: idx write, coalesced codebook row gather, channel-first z_q write
// + loss (z from zb). No global final_ buffer, no extra dispatch.
// ---------------------------------------------------------------------------
__global__ __launch_bounds__(256) void vq_out_kernel(
    const float* __restrict__ z, const float* __restrict__ cb,
    const float* __restrict__ e2, const u32* __restrict__ best4,
    float* __restrict__ out, float* __restrict__ idxf,
    float* __restrict__ loss)
{
    __shared__ float zb[32][260];   // 33.3 KB  z block (exact dots + loss)
    __shared__ float zq[32][257];   // 32.9 KB  gathered codebook rows
    __shared__ u64  sfinal[32];
    __shared__ int  nidx[32];
    __shared__ u32  work[2048];     // (px<<13)|n  (hard cap 32*64)
    __shared__ u32  scans[512];     // (px<<4)|hs  (hard cap 32*16)
    __shared__ int  nwork, nscan;

    const int tid = threadIdx.x;
    const int p0  = blockIdx.x * 32;
    const int bb  = p0 >> 10, hw0 = p0 & 1023;

    if (tid == 0) { nwork = 0; nscan = 0; }
    if (tid < 32) sfinal[tid] = ~0ULL;
    __syncthreads();

    // Phase A ------------------------------------------------------------
    {
        const int pix = tid >> 3;          // 0..31
        const int hp  = (tid & 7) * 2;     // this thread's 2 half-slices
        const u32* src = &best4[((size_t)(p0 + pix) * 16 + hp) * 4];
        const u32x4 kv0 = *(const u32x4*)(src);
        const u32x4 kv1 = *(const u32x4*)(src + 4);
        u32 lmin = min(min(kv0[0], kv0[1]), min(kv0[2], kv0[3]));
        lmin = min(lmin, min(min(kv1[0], kv1[1]), min(kv1[2], kv1[3])));
        u32 mn = lmin;
        #pragma unroll
        for (int m = 1; m < 8; m <<= 1) mn = min(mn, (u32)__shfl_xor((int)mn, m));
        const float thr = kval(mn) + DELTA;
        int c8 = 0;
        #pragma unroll
        for (int j = 0; j < 4; ++j) c8 += (kval(kv0[j]) <= thr) ? 1 : 0;
        #pragma unroll
        for (int j = 0; j < 4; ++j) c8 += (kval(kv1[j]) <= thr) ? 1 : 0;
        int cnt = c8;
        #pragma unroll
        for (int m = 1; m < 8; m <<= 1) cnt += __shfl_xor(cnt, m);
        const int s0 = (kval(kv0[3]) <= thr) ? 1 : 0;
        const int s1 = (kval(kv1[3]) <= thr) ? 1 : 0;
        int anysusp = s0 + s1;
        #pragma unroll
        for (int m = 1; m < 8; m <<= 1) anysusp += __shfl_xor(anysusp, m);

        if (cnt == 1 && anysusp == 0) {
            if (lmin == mn) sfinal[pix] = (u64)(mn & 8191u);
        } else {
            if (c8 > 0) {
                const int base = atomicAdd(&nwork, c8);
                int k = 0;
                #pragma unroll
                for (int j = 0; j < 4; ++j)
                    if (kval(kv0[j]) <= thr)
                        work[base + (k++)] = ((u32)pix << 13) | (kv0[j] & 8191u);
                #pragma unroll
                for (int j = 0; j < 4; ++j)
                    if (kval(kv1[j]) <= thr)
                        work[base + (k++)] = ((u32)pix << 13) | (kv1[j] & 8191u);
            }
            if (s0) scans[atomicAdd(&nscan, 1)] = ((u32)pix << 4) | (u32)hp;
            if (s1) scans[atomicAdd(&nscan, 1)] = ((u32)pix << 4) | (u32)(hp + 1);
        }
    }
    __syncthreads();

    // Stage zb (always -- feeds exact dots AND the loss) -------------------
    #pragma unroll
    for (int i = 0; i < 32; ++i) {
        const int idx = i * 256 + tid;
        const int c = idx >> 5, px = idx & 31;
        zb[px][c] = z[(size_t)bb * BCHW + (size_t)c * HW + hw0 + px];
    }
    __syncthreads();

    const int nw = nwork, ns = nscan;

    // Phase C: one thread per passer candidate ----------------------------
    for (int i = tid; i < nw; i += 256) {
        const u32 e = work[i];
        const int px = (int)(e >> 13), n = (int)(e & 8191u);
        const float* er = cb + (size_t)n * KD;
        float acc = 0.f;
        #pragma unroll 4
        for (int k = 0; k < KD; k += 4) {
            const f32x4 zv = *(const f32x4*)&zb[px][k];
            const f32x4 ev = *(const f32x4*)(er + k);
            acc += zv[0]*ev[0] + zv[1]*ev[1] + zv[2]*ev[2] + zv[3]*ev[3];
        }
        const float s = 0.5f * e2[n] - acc;
        atomicMin(&sfinal[px], ((u64)fkey(s) << 32) | (u32)n);
    }

    // Phase D: suspect half-slice scans (rare) ----------------------------
    for (int si = 0; si < ns; ++si) {
        const u32 e = scans[si];
        const int px = (int)(e >> 4), hx = (int)(e & 15u);
        u64 bku = ~0ULL;
        #pragma unroll
        for (int h = 0; h < 2; ++h) {
            const int ci = tid + h * 256;
            const int n = (hx >> 1) * 1024 + (ci >> 6) * 128
                        + (hx & 1) * 64 + (ci & 63);
            const float* er = cb + (size_t)n * KD;
            float acc = 0.f;
            #pragma unroll 4
            for (int k = 0; k < KD; k += 4) {
                const f32x4 zv = *(const f32x4*)&zb[px][k];
                const f32x4 ev = *(const f32x4*)(er + k);
                acc += zv[0]*ev[0] + zv[1]*ev[1] + zv[2]*ev[2] + zv[3]*ev[3];
            }
            const float s = 0.5f * e2[n] - acc;
            const u64 pk = ((u64)fkey(s) << 32) | (u32)n;
            bku = min(bku, pk);
        }
        #pragma unroll
        for (int m = 1; m < 64; m <<= 1) {
            const u64 o = (u64)__shfl_xor((long long)bku, m);
            bku = min(bku, o);
        }
        if ((tid & 63) == 0) atomicMin(&sfinal[px], bku);
    }
    __syncthreads();

    // Winners -> idx output ------------------------------------------------
    if (tid < 32) {
        const int n = (int)((u32)sfinal[tid] & 8191u);
        nidx[tid] = n;
        idxf[p0 + tid] = (float)n;
    }
    __syncthreads();

    // Gather 32 codebook rows coalesced -----------------------------------
    {
        const int r = tid >> 3, i = tid & 7;
        const float* src = cb + (size_t)nidx[r] * KD;
        #pragma unroll
        for (int j = 0; j < 8; ++j) {
            const int col = i * 4 + j * 32;
            const f32x4 v = *(const f32x4*)(src + col);
            zq[r][col + 0] = v[0]; zq[r][col + 1] = v[1];
            zq[r][col + 2] = v[2]; zq[r][col + 3] = v[3];
        }
    }
    __syncthreads();

    // Channel-first z_q write + loss (z from zb) --------------------------
    const int p4 = (tid & 7) * 4;
    const int cg = tid >> 3;
    float ls = 0.f;
    #pragma unroll
    for (int ii = 0; ii < 8; ++ii) {
        const int c = cg + 32 * ii;
        const size_t e = (size_t)bb * BCHW + (size_t)c * HW + hw0 + p4;
        f32x4 v;
        v[0] = zq[p4 + 0][c]; v[1] = zq[p4 + 1][c];
        v[2] = zq[p4 + 2][c]; v[3] = zq[p4 + 3][c];
        *(f32x4*)(out + e) = v;
        const float d0 = v[0] - zb[p4 + 0][c], d1 = v[1] - zb[p4 + 1][c];
        const float d2 = v[2] - zb[p4 + 2][c], d3 = v[3] - zb[p4 + 3][c];
        ls += d0 * d0 + d1 * d1 + d2 * d2 + d3 * d3;
    }
    #pragma unroll
    for (int m = 1; m < 64; m <<= 1) ls += __shfl_xor(ls, m);
    if ((tid & 63) == 0) atomicAdd(loss, ls * (1.25f / 4194304.f));
}

// ---------------------------------------------------------------------------
extern "C" void kernel_launch(void* const* d_in, const int* in_sizes, int n_in,
                              void* d_out, int out_size, void* d_ws, size_t ws_size,
                              hipStream_t stream) {
    const float* z  = (const float*)d_in[0];
    const float* cb = (const float*)d_in[1];
    float* out  = (float*)d_out;
    float* idxf = out + 4194304;
    float* loss = out + 4210688;
    // scratch inside the z_q region of d_out (fully overwritten at the end):
    char* ob = (char*)d_out;
    short* zh    = (short*)ob;                    // [0 .. 8MB)   bf16 z [p][k]
    short* eh    = (short*)(ob + 8388608);        // [8 .. 12MB)  bf16 codebook
    u32*   best4 = (u32*)(ob + 12582912);         // [12 .. 16MB) 16384 x 16 x 4 u32

    float* e2 = (float*)d_ws;                // 32 KB

    hipMemsetAsync(loss, 0, 4, stream);

    vq_prep<<<2048, 256, 0, stream>>>(cb, eh, e2);
    vq_zh<<<dim3(16, 4, 16), 256, 0, stream>>>(z, zh);
    vq_gemm<<<dim3(NPIX / 128, NE / (NT * 128)), 512, 0, stream>>>(zh, eh, best4);
    vq_out_kernel<<<NPIX / 32, 256, 0, stream>>>(z, cb, e2, best4, out, idxf, loss);
}

// Round 26
// 178.169 us; speedup vs baseline: 1.6091x; 1.0086x over previous
//
#include <hip/hip_runtime.h>
#include <float.h>

#define NPIX 16384    // B*H*W pixels
#define NE   8192     // codebook entries
#define KD   256      // channels
#define HW   1024
#define BCHW 262144
#define NT   8        // N-tiles (128 codes) per wg -> wg spans 1024 codes (slice)
#define DELTA 2.5e-4f // rescue window: bf16 err + 2x key quant + margin
#define KMASK 0xFFFFE000u

typedef __attribute__((ext_vector_type(8))) short short8;
typedef __attribute__((ext_vector_type(4))) short short4v;
typedef __attribute__((ext_vector_type(4))) float f32x4;
typedef __attribute__((ext_vector_type(4))) unsigned int u32x4;
typedef unsigned long long u64;
typedef unsigned int u32;

__device__ __forceinline__ u32 fkey(float f) {
    u32 u = __float_as_uint(f);
    return u ^ ((u >> 31) ? 0xFFFFFFFFu : 0x80000000u);
}
__device__ __forceinline__ short bf16rne(float f) {
    u32 u = __float_as_uint(f);
    u += 0x7FFFu + ((u >> 16) & 1u);
    return (short)(u >> 16);
}
__device__ __forceinline__ float kval(u32 pk) {   // packed key -> quantized value
    return __uint_as_float(pk & KMASK);
}

#define GLDS(gp, lp) __builtin_amdgcn_global_load_lds( \
    (const __attribute__((address_space(1))) void*)(gp), \
    (__attribute__((address_space(3))) void*)(lp), 16, 0, 0)

// ---------------------------------------------------------------------------
// FUSED prep: blocks [0,2048): codebook -> bf16 + e2 (one wave per row);
//             blocks [2048,3072): z [b][k][hw] fp32 -> zh [p][k] bf16
//             (transpose via LDS). The two halves are independent and run
//             concurrently across CUs (was: two serialized dispatches).
// ---------------------------------------------------------------------------
__global__ __launch_bounds__(256) void vq_prep2(
    const float* __restrict__ cb, const float* __restrict__ z,
    short* __restrict__ eh, float* __restrict__ e2, short* __restrict__ zh)
{
    __shared__ float ts[64][65];
    const int tid = threadIdx.x;

    if (blockIdx.x < 2048) {
        // ---- codebook half ----
        const int row  = ((int)blockIdx.x * 256 + tid) >> 6;
        const int lane = tid & 63;
        const f32x4 v = *(const f32x4*)(cb + (size_t)row * KD + lane * 4);
        short4v h;
        h[0] = bf16rne(v[0]); h[1] = bf16rne(v[1]);
        h[2] = bf16rne(v[2]); h[3] = bf16rne(v[3]);
        *(short4v*)(eh + (size_t)row * KD + lane * 4) = h;
        float s = v[0]*v[0] + v[1]*v[1] + v[2]*v[2] + v[3]*v[3];
        #pragma unroll
        for (int m = 1; m < 64; m <<= 1) s += __shfl_xor(s, m);
        if (lane == 0) e2[row] = s;
    } else {
        // ---- z-transpose half ----
        const int bid = (int)blockIdx.x - 2048;      // 0..1023
        const int hw0 = (bid & 15) * 64;
        const int k0  = ((bid >> 4) & 3) * 64;
        const int b   = bid >> 6;
        const int pl  = tid & 63, kk = tid >> 6;
        #pragma unroll
        for (int i = 0; i < 16; ++i) {
            const int k = kk + 4 * i;
            ts[k][pl] = z[b * BCHW + (k0 + k) * HW + hw0 + pl];
        }
        __syncthreads();
        const int tx = tid & 15, ty = tid >> 4;
        #pragma unroll
        for (int j = 0; j < 4; ++j) {
            const int p = ty + 16 * j;
            short4v v;
            #pragma unroll
            for (int q = 0; q < 4; ++q) v[q] = bf16rne(ts[tx * 4 + q][p]);
            *(short4v*)(zh + (size_t)(b * HW + hw0 + p) * KD + k0 + tx * 4) = v;
        }
    }
}

// ---------------------------------------------------------------------------
// Fused GEMM + per-(pixel, HALF-slice) top-4 tracking. (R24, unchanged)
// 512 threads = 8 waves (4M x 2N), per-wave tile 32 px x 64 codes,
// 4 static B buffers, 1 barrier/step, counted vmcnt(1), A in registers.
// ---------------------------------------------------------------------------
__global__ __launch_bounds__(512, 2) void vq_gemm(
    const short* __restrict__ zh, const short* __restrict__ eh,
    u32* __restrict__ best4)
{
    __shared__ short Bs[4][4096];   // [buf][128 rows x 32 k]  (32 KB)

    const int tid  = threadIdx.x;
    const int lane = tid & 63;
    const int w    = tid >> 6;          // 0..7
    const int wm   = w >> 1, wn = w & 1;
    const int lr   = lane & 15;
    const int p0   = blockIdx.x * 128;
    const int nb0  = blockIdx.y * (NT * 128);

    const int sr = lane >> 2;           // 0..15 row in wave's 16-row block
    const int ss = (lane & 3) ^ ((sr >> 1) & 3);
    const int q   = lane >> 4;
    const int rsw = (lr >> 1) & 3;

    u32 b1[2][4], b2[2][4];
    #pragma unroll
    for (int m = 0; m < 2; ++m)
        #pragma unroll
        for (int r = 0; r < 4; ++r) { b1[m][r] = 0xFFFFFFFFu; b2[m][r] = 0xFFFFFFFFu; }

    // ---- A-fragments: direct global -> register, once per wg ----
    short8 afr[2][8];
    #pragma unroll
    for (int m = 0; m < 2; ++m) {
        const size_t rowb = (size_t)(p0 + wm * 32 + m * 16 + lr) * KD;
        #pragma unroll
        for (int ks = 0; ks < 8; ++ks)
            afr[m][ks] = *(const short8*)(zh + rowb + ks * 32 + q * 8);
    }
    asm volatile("s_waitcnt vmcnt(0)" ::: "memory");

    #define STAGEB(nt_, t_, buf_) do {                                         \
        const int k0_ = (t_) * 32;                                             \
        const int n0_ = nb0 + (nt_) * 128;                                     \
        GLDS(eh + (size_t)(n0_ + w * 16 + sr) * KD + k0_ + ss * 8,             \
             &Bs[buf_][w * 512]);                                              \
    } while (0)

    f32x4 acc[2][4];

    STAGEB(0, 0, 0);
    STAGEB(0, 1, 1);

    #pragma unroll 1
    for (int nt = 0; nt < NT; ++nt) {
        const bool lastnt = (nt == NT - 1);
        #pragma unroll
        for (int t = 0; t < 8; ++t) {
            if (lastnt && t == 7) asm volatile("s_waitcnt vmcnt(0)" ::: "memory");
            else                  asm volatile("s_waitcnt vmcnt(1)" ::: "memory");
            __builtin_amdgcn_sched_barrier(0);
            __builtin_amdgcn_s_barrier();

            if (t < 6)        { STAGEB(nt, t + 2, (t + 2) & 3); }
            else if (!lastnt) { STAGEB(nt + 1, t - 6, (t - 6) & 3); }

            if (t == 0) {
                #pragma unroll
                for (int m = 0; m < 2; ++m)
                    #pragma unroll
                    for (int nf = 0; nf < 4; ++nf)
                        acc[m][nf] = (f32x4){0.f, 0.f, 0.f, 0.f};
            }

            short8 bfv[4];
            #pragma unroll
            for (int nf = 0; nf < 4; ++nf) {
                const int row = wn * 64 + nf * 16 + lr;
                bfv[nf] = *(const short8*)&Bs[t & 3][row * 32 + ((q ^ rsw) * 8)];
            }
            #pragma unroll
            for (int m = 0; m < 2; ++m)
                #pragma unroll
                for (int nf = 0; nf < 4; ++nf)
                    acc[m][nf] = __builtin_amdgcn_mfma_f32_16x16x32_bf16(
                        afr[m][t], bfv[nf], acc[m][nf], 0, 0, 0);

            if (t == 7) {
                const u32 nbase = (u32)(nb0 + nt * 128 + wn * 64 + lr);
                #pragma unroll
                for (int m = 0; m < 2; ++m) {
                    #pragma unroll
                    for (int r = 0; r < 4; ++r) {
                        u32 pk0 = (__float_as_uint(0.0625f - acc[m][0][r]) & KMASK) | (nbase);
                        u32 pk1 = (__float_as_uint(0.0625f - acc[m][1][r]) & KMASK) | (nbase + 16u);
                        u32 pk2 = (__float_as_uint(0.0625f - acc[m][2][r]) & KMASK) | (nbase + 32u);
                        u32 pk3 = (__float_as_uint(0.0625f - acc[m][3][r]) & KMASK) | (nbase + 48u);
                        const u32 lo01 = min(pk0, pk1), hi01 = max(pk0, pk1);
                        const u32 lo23 = min(pk2, pk3), hi23 = max(pk2, pk3);
                        const u32 m1 = min(lo01, lo23);
                        const u32 m2 = min(max(lo01, lo23), min(hi01, hi23));
                        const u32 nb1 = min(b1[m][r], m1);
                        const u32 nb2 = min(max(b1[m][r], m1), min(b2[m][r], m2));
                        b1[m][r] = nb1; b2[m][r] = nb2;
                    }
                }
            }
        }
    }
    #undef STAGEB

    // ---- wg-end: top-4 of this wave's lane-union per pixel ----
    const int g = lane >> 4;
    const int hs = blockIdx.y * 2 + wn;          // half-slice: single writer
    #pragma unroll
    for (int m = 0; m < 2; ++m) {
        #pragma unroll
        for (int r = 0; r < 4; ++r) {
            u32 a = b1[m][r], b = b2[m][r];
            u32 o[4];
            #pragma unroll
            for (int j = 0; j < 4; ++j) {
                u32 mm = a;
                #pragma unroll
                for (int msk = 1; msk < 16; msk <<= 1)
                    mm = min(mm, (u32)__shfl_xor((int)mm, msk));
                o[j] = mm;
                if (a == mm) { a = b; b = 0xFFFFFFFFu; }
            }
            if (lr == 0) {
                const int prow = p0 + wm * 32 + m * 16 + g * 4 + r;
                u32x4 ov; ov[0] = o[0]; ov[1] = o[1]; ov[2] = o[2]; ov[3] = o[3];
                *(u32x4*)&best4[((size_t)prow * 16 + hs) * 4] = ov;
            }
        }
    }
}

// ---------------------------------------------------------------------------
// FUSED exact + output: one wg per 32 pixels, 256 threads. (R25, unchanged)
// ---------------------------------------------------------------------------
__global__ __launch_bounds__(256) void vq_out_kernel(
    const float* __restrict__ z, const float* __restrict__ cb,
    const float* __restrict__ e2, const u32* __restrict__ best4,
    float* __restrict__ out, float* __restrict__ idxf,
    float* __restrict__ loss)
{
    __shared__ float zb[32][260];   // 33.3 KB  z block (exact dots + loss)
    __shared__ float zq[32][257];   // 32.9 KB  gathered codebook rows
    __shared__ u64  sfinal[32];
    __shared__ int  nidx[32];
    __shared__ u32  work[2048];     // (px<<13)|n  (hard cap 32*64)
    __shared__ u32  scans[512];     // (px<<4)|hs  (hard cap 32*16)
    __shared__ int  nwork, nscan;

    const int tid = threadIdx.x;
    const int p0  = blockIdx.x * 32;
    const int bb  = p0 >> 10, hw0 = p0 & 1023;

    if (tid == 0) { nwork = 0; nscan = 0; }
    if (tid < 32) sfinal[tid] = ~0ULL;
    __syncthreads();

    // Phase A ------------------------------------------------------------
    {
        const int pix = tid >> 3;          // 0..31
        const int hp  = (tid & 7) * 2;     // this thread's 2 half-slices
        const u32* src = &best4[((size_t)(p0 + pix) * 16 + hp) * 4];
        const u32x4 kv0 = *(const u32x4*)(src);
        const u32x4 kv1 = *(const u32x4*)(src + 4);
        u32 lmin = min(min(kv0[0], kv0[1]), min(kv0[2], kv0[3]));
        lmin = min(lmin, min(min(kv1[0], kv1[1]), min(kv1[2], kv1[3])));
        u32 mn = lmin;
        #pragma unroll
        for (int m = 1; m < 8; m <<= 1) mn = min(mn, (u32)__shfl_xor((int)mn, m));
        const float thr = kval(mn) + DELTA;
        int c8 = 0;
        #pragma unroll
        for (int j = 0; j < 4; ++j) c8 += (kval(kv0[j]) <= thr) ? 1 : 0;
        #pragma unroll
        for (int j = 0; j < 4; ++j) c8 += (kval(kv1[j]) <= thr) ? 1 : 0;
        int cnt = c8;
        #pragma unroll
        for (int m = 1; m < 8; m <<= 1) cnt += __shfl_xor(cnt, m);
        const int s0 = (kval(kv0[3]) <= thr) ? 1 : 0;
        const int s1 = (kval(kv1[3]) <= thr) ? 1 : 0;
        int anysusp = s0 + s1;
        #pragma unroll
        for (int m = 1; m < 8; m <<= 1) anysusp += __shfl_xor(anysusp, m);

        if (cnt == 1 && anysusp == 0) {
            if (lmin == mn) sfinal[pix] = (u64)(mn & 8191u);
        } else {
            if (c8 > 0) {
                const int base = atomicAdd(&nwork, c8);
                int k = 0;
                #pragma unroll
                for (int j = 0; j < 4; ++j)
                    if (kval(kv0[j]) <= thr)
                        work[base + (k++)] = ((u32)pix << 13) | (kv0[j] & 8191u);
                #pragma unroll
                for (int j = 0; j < 4; ++j)
                    if (kval(kv1[j]) <= thr)
                        work[base + (k++)] = ((u32)pix << 13) | (kv1[j] & 8191u);
            }
            if (s0) scans[atomicAdd(&nscan, 1)] = ((u32)pix << 4) | (u32)hp;
            if (s1) scans[atomicAdd(&nscan, 1)] = ((u32)pix << 4) | (u32)(hp + 1);
        }
    }
    __syncthreads();

    // Stage zb (always -- feeds exact dots AND the loss) -------------------
    #pragma unroll
    for (int i = 0; i < 32; ++i) {
        const int idx = i * 256 + tid;
        const int c = idx >> 5, px = idx & 31;
        zb[px][c] = z[(size_t)bb * BCHW + (size_t)c * HW + hw0 + px];
    }
    __syncthreads();

    const int nw = nwork, ns = nscan;

    // Phase C: one thread per passer candidate ----------------------------
    for (int i = tid; i < nw; i += 256) {
        const u32 e = work[i];
        const int px = (int)(e >> 13), n = (int)(e & 8191u);
        const float* er = cb + (size_t)n * KD;
        float acc = 0.f;
        #pragma unroll 4
        for (int k = 0; k < KD; k += 4) {
            const f32x4 zv = *(const f32x4*)&zb[px][k];
            const f32x4 ev = *(const f32x4*)(er + k);
            acc += zv[0]*ev[0] + zv[1]*ev[1] + zv[2]*ev[2] + zv[3]*ev[3];
        }
        const float s = 0.5f * e2[n] - acc;
        atomicMin(&sfinal[px], ((u64)fkey(s) << 32) | (u32)n);
    }

    // Phase D: suspect half-slice scans (rare) ----------------------------
    for (int si = 0; si < ns; ++si) {
        const u32 e = scans[si];
        const int px = (int)(e >> 4), hx = (int)(e & 15u);
        u64 bku = ~0ULL;
        #pragma unroll
        for (int h = 0; h < 2; ++h) {
            const int ci = tid + h * 256;
            const int n = (hx >> 1) * 1024 + (ci >> 6) * 128
                        + (hx & 1) * 64 + (ci & 63);
            const float* er = cb + (size_t)n * KD;
            float acc = 0.f;
            #pragma unroll 4
            for (int k = 0; k < KD; k += 4) {
                const f32x4 zv = *(const f32x4*)&zb[px][k];
                const f32x4 ev = *(const f32x4*)(er + k);
                acc += zv[0]*ev[0] + zv[1]*ev[1] + zv[2]*ev[2] + zv[3]*ev[3];
            }
            const float s = 0.5f * e2[n] - acc;
            const u64 pk = ((u64)fkey(s) << 32) | (u32)n;
            bku = min(bku, pk);
        }
        #pragma unroll
        for (int m = 1; m < 64; m <<= 1) {
            const u64 o = (u64)__shfl_xor((long long)bku, m);
            bku = min(bku, o);
        }
        if ((tid & 63) == 0) atomicMin(&sfinal[px], bku);
    }
    __syncthreads();

    // Winners -> idx output ------------------------------------------------
    if (tid < 32) {
        const int n = (int)((u32)sfinal[tid] & 8191u);
        nidx[tid] = n;
        idxf[p0 + tid] = (float)n;
    }
    __syncthreads();

    // Gather 32 codebook rows coalesced -----------------------------------
    {
        const int r = tid >> 3, i = tid & 7;
        const float* src = cb + (size_t)nidx[r] * KD;
        #pragma unroll
        for (int j = 0; j < 8; ++j) {
            const int col = i * 4 + j * 32;
            const f32x4 v = *(const f32x4*)(src + col);
            zq[r][col + 0] = v[0]; zq[r][col + 1] = v[1];
            zq[r][col + 2] = v[2]; zq[r][col + 3] = v[3];
        }
    }
    __syncthreads();

    // Channel-first z_q write + loss (z from zb) --------------------------
    const int p4 = (tid & 7) * 4;
    const int cg = tid >> 3;
    float ls = 0.f;
    #pragma unroll
    for (int ii = 0; ii < 8; ++ii) {
        const int c = cg + 32 * ii;
        const size_t e = (size_t)bb * BCHW + (size_t)c * HW + hw0 + p4;
        f32x4 v;
        v[0] = zq[p4 + 0][c]; v[1] = zq[p4 + 1][c];
        v[2] = zq[p4 + 2][c]; v[3] = zq[p4 + 3][c];
        *(f32x4*)(out + e) = v;
        const float d0 = v[0] - zb[p4 + 0][c], d1 = v[1] - zb[p4 + 1][c];
        const float d2 = v[2] - zb[p4 + 2][c], d3 = v[3] - zb[p4 + 3][c];
        ls += d0 * d0 + d1 * d1 + d2 * d2 + d3 * d3;
    }
    #pragma unroll
    for (int m = 1; m < 64; m <<= 1) ls += __shfl_xor(ls, m);
    if ((tid & 63) == 0) atomicAdd(loss, ls * (1.25f / 4194304.f));
}

// ---------------------------------------------------------------------------
extern "C" void kernel_launch(void* const* d_in, const int* in_sizes, int n_in,
                              void* d_out, int out_size, void* d_ws, size_t ws_size,
                              hipStream_t stream) {
    const float* z  = (const float*)d_in[0];
    const float* cb = (const float*)d_in[1];
    float* out  = (float*)d_out;
    float* idxf = out + 4194304;
    float* loss = out + 4210688;
    // scratch inside the z_q region of d_out (fully overwritten at the end):
    char* ob = (char*)d_out;
    short* zh    = (short*)ob;                    // [0 .. 8MB)   bf16 z [p][k]
    short* eh    = (short*)(ob + 8388608);        // [8 .. 12MB)  bf16 codebook
    u32*   best4 = (u32*)(ob + 12582912);         // [12 .. 16MB) 16384 x 16 x 4 u32

    float* e2 = (float*)d_ws;                // 32 KB

    hipMemsetAsync(loss, 0, 4, stream);

    vq_prep2<<<3072, 256, 0, stream>>>(cb, z, eh, e2, zh);
    vq_gemm<<<dim3(NPIX / 128, NE / (NT * 128)), 512, 0, stream>>>(zh, eh, best4);
    vq_out_kernel<<<NPIX / 32, 256, 0, stream>>>(z, cb, e2, best4, out, idxf, loss);
}

// Round 27
// 173.049 us; speedup vs baseline: 1.6567x; 1.0296x over previous
//
#include <hip/hip_runtime.h>
#include <float.h>

#define NPIX 16384    // B*H*W pixels
#define NE   8192     // codebook entries
#define KD   256      // channels
#define HW   1024
#define BCHW 262144
#define NT   8        // N-tiles (128 codes) per wg -> wg spans 1024 codes (slice)
#define DELTA 2.5e-4f // rescue window: bf16 err + 2x key quant + margin
#define KMASK 0xFFFFE000u

typedef __attribute__((ext_vector_type(8))) short short8;
typedef __attribute__((ext_vector_type(4))) short short4v;
typedef __attribute__((ext_vector_type(4))) float f32x4;
typedef __attribute__((ext_vector_type(4))) unsigned int u32x4;
typedef unsigned long long u64;
typedef unsigned int u32;

__device__ __forceinline__ u32 fkey(float f) {
    u32 u = __float_as_uint(f);
    return u ^ ((u >> 31) ? 0xFFFFFFFFu : 0x80000000u);
}
__device__ __forceinline__ short bf16rne(float f) {
    u32 u = __float_as_uint(f);
    u += 0x7FFFu + ((u >> 16) & 1u);
    return (short)(u >> 16);
}
__device__ __forceinline__ float kval(u32 pk) {   // packed key -> quantized value
    return __uint_as_float(pk & KMASK);
}

#define GLDS(gp, lp) __builtin_amdgcn_global_load_lds( \
    (const __attribute__((address_space(1))) void*)(gp), \
    (__attribute__((address_space(3))) void*)(lp), 16, 0, 0)

// ---------------------------------------------------------------------------
// FUSED prep: blocks [0,2048): codebook -> bf16 + e2 (one wave per row);
//             blocks [2048,3072): z [b][k][hw] fp32 -> zh [p][k] bf16.
// ---------------------------------------------------------------------------
__global__ __launch_bounds__(256) void vq_prep2(
    const float* __restrict__ cb, const float* __restrict__ z,
    short* __restrict__ eh, float* __restrict__ e2, short* __restrict__ zh)
{
    __shared__ float ts[64][65];
    const int tid = threadIdx.x;

    if (blockIdx.x < 2048) {
        const int row  = ((int)blockIdx.x * 256 + tid) >> 6;
        const int lane = tid & 63;
        const f32x4 v = *(const f32x4*)(cb + (size_t)row * KD + lane * 4);
        short4v h;
        h[0] = bf16rne(v[0]); h[1] = bf16rne(v[1]);
        h[2] = bf16rne(v[2]); h[3] = bf16rne(v[3]);
        *(short4v*)(eh + (size_t)row * KD + lane * 4) = h;
        float s = v[0]*v[0] + v[1]*v[1] + v[2]*v[2] + v[3]*v[3];
        #pragma unroll
        for (int m = 1; m < 64; m <<= 1) s += __shfl_xor(s, m);
        if (lane == 0) e2[row] = s;
    } else {
        const int bid = (int)blockIdx.x - 2048;      // 0..1023
        const int hw0 = (bid & 15) * 64;
        const int k0  = ((bid >> 4) & 3) * 64;
        const int b   = bid >> 6;
        const int pl  = tid & 63, kk = tid >> 6;
        #pragma unroll
        for (int i = 0; i < 16; ++i) {
            const int k = kk + 4 * i;
            ts[k][pl] = z[b * BCHW + (k0 + k) * HW + hw0 + pl];
        }
        __syncthreads();
        const int tx = tid & 15, ty = tid >> 4;
        #pragma unroll
        for (int j = 0; j < 4; ++j) {
            const int p = ty + 16 * j;
            short4v v;
            #pragma unroll
            for (int q = 0; q < 4; ++q) v[q] = bf16rne(ts[tx * 4 + q][p]);
            *(short4v*)(zh + (size_t)(b * HW + hw0 + p) * KD + k0 + tx * 4) = v;
        }
    }
}

// ---------------------------------------------------------------------------
// Fused GEMM + per-(pixel, HALF-slice) top-4 tracking. (R24 + T5 setprio)
// 512 threads = 8 waves (4M x 2N), per-wave tile 32 px x 64 codes,
// 4 static B buffers, 1 barrier/step, counted vmcnt(1), A in registers.
// NEW: s_setprio(1) around the MFMA cluster -- with 4 waves/SIMD from 2
// phase-offset wgs, the CU scheduler can prefer matrix-issuing waves.
// ---------------------------------------------------------------------------
__global__ __launch_bounds__(512, 2) void vq_gemm(
    const short* __restrict__ zh, const short* __restrict__ eh,
    u32* __restrict__ best4)
{
    __shared__ short Bs[4][4096];   // [buf][128 rows x 32 k]  (32 KB)

    const int tid  = threadIdx.x;
    const int lane = tid & 63;
    const int w    = tid >> 6;          // 0..7
    const int wm   = w >> 1, wn = w & 1;
    const int lr   = lane & 15;
    const int p0   = blockIdx.x * 128;
    const int nb0  = blockIdx.y * (NT * 128);

    const int sr = lane >> 2;           // 0..15 row in wave's 16-row block
    const int ss = (lane & 3) ^ ((sr >> 1) & 3);
    const int q   = lane >> 4;
    const int rsw = (lr >> 1) & 3;

    u32 b1[2][4], b2[2][4];
    #pragma unroll
    for (int m = 0; m < 2; ++m)
        #pragma unroll
        for (int r = 0; r < 4; ++r) { b1[m][r] = 0xFFFFFFFFu; b2[m][r] = 0xFFFFFFFFu; }

    // ---- A-fragments: direct global -> register, once per wg ----
    short8 afr[2][8];
    #pragma unroll
    for (int m = 0; m < 2; ++m) {
        const size_t rowb = (size_t)(p0 + wm * 32 + m * 16 + lr) * KD;
        #pragma unroll
        for (int ks = 0; ks < 8; ++ks)
            afr[m][ks] = *(const short8*)(zh + rowb + ks * 32 + q * 8);
    }
    asm volatile("s_waitcnt vmcnt(0)" ::: "memory");

    #define STAGEB(nt_, t_, buf_) do {                                         \
        const int k0_ = (t_) * 32;                                             \
        const int n0_ = nb0 + (nt_) * 128;                                     \
        GLDS(eh + (size_t)(n0_ + w * 16 + sr) * KD + k0_ + ss * 8,             \
             &Bs[buf_][w * 512]);                                              \
    } while (0)

    f32x4 acc[2][4];

    STAGEB(0, 0, 0);
    STAGEB(0, 1, 1);

    #pragma unroll 1
    for (int nt = 0; nt < NT; ++nt) {
        const bool lastnt = (nt == NT - 1);
        #pragma unroll
        for (int t = 0; t < 8; ++t) {
            if (lastnt && t == 7) asm volatile("s_waitcnt vmcnt(0)" ::: "memory");
            else                  asm volatile("s_waitcnt vmcnt(1)" ::: "memory");
            __builtin_amdgcn_sched_barrier(0);
            __builtin_amdgcn_s_barrier();

            if (t < 6)        { STAGEB(nt, t + 2, (t + 2) & 3); }
            else if (!lastnt) { STAGEB(nt + 1, t - 6, (t - 6) & 3); }

            if (t == 0) {
                #pragma unroll
                for (int m = 0; m < 2; ++m)
                    #pragma unroll
                    for (int nf = 0; nf < 4; ++nf)
                        acc[m][nf] = (f32x4){0.f, 0.f, 0.f, 0.f};
            }

            short8 bfv[4];
            #pragma unroll
            for (int nf = 0; nf < 4; ++nf) {
                const int row = wn * 64 + nf * 16 + lr;
                bfv[nf] = *(const short8*)&Bs[t & 3][row * 32 + ((q ^ rsw) * 8)];
            }
            __builtin_amdgcn_s_setprio(1);
            #pragma unroll
            for (int m = 0; m < 2; ++m)
                #pragma unroll
                for (int nf = 0; nf < 4; ++nf)
                    acc[m][nf] = __builtin_amdgcn_mfma_f32_16x16x32_bf16(
                        afr[m][t], bfv[nf], acc[m][nf], 0, 0, 0);
            __builtin_amdgcn_s_setprio(0);

            if (t == 7) {
                const u32 nbase = (u32)(nb0 + nt * 128 + wn * 64 + lr);
                #pragma unroll
                for (int m = 0; m < 2; ++m) {
                    #pragma unroll
                    for (int r = 0; r < 4; ++r) {
                        u32 pk0 = (__float_as_uint(0.0625f - acc[m][0][r]) & KMASK) | (nbase);
                        u32 pk1 = (__float_as_uint(0.0625f - acc[m][1][r]) & KMASK) | (nbase + 16u);
                        u32 pk2 = (__float_as_uint(0.0625f - acc[m][2][r]) & KMASK) | (nbase + 32u);
                        u32 pk3 = (__float_as_uint(0.0625f - acc[m][3][r]) & KMASK) | (nbase + 48u);
                        const u32 lo01 = min(pk0, pk1), hi01 = max(pk0, pk1);
                        const u32 lo23 = min(pk2, pk3), hi23 = max(pk2, pk3);
                        const u32 m1 = min(lo01, lo23);
                        const u32 m2 = min(max(lo01, lo23), min(hi01, hi23));
                        const u32 nb1 = min(b1[m][r], m1);
                        const u32 nb2 = min(max(b1[m][r], m1), min(b2[m][r], m2));
                        b1[m][r] = nb1; b2[m][r] = nb2;
                    }
                }
            }
        }
    }
    #undef STAGEB

    // ---- wg-end: top-4 of this wave's lane-union per pixel ----
    const int g = lane >> 4;
    const int hs = blockIdx.y * 2 + wn;          // half-slice: single writer
    #pragma unroll
    for (int m = 0; m < 2; ++m) {
        #pragma unroll
        for (int r = 0; r < 4; ++r) {
            u32 a = b1[m][r], b = b2[m][r];
            u32 o[4];
            #pragma unroll
            for (int j = 0; j < 4; ++j) {
                u32 mm = a;
                #pragma unroll
                for (int msk = 1; msk < 16; msk <<= 1)
                    mm = min(mm, (u32)__shfl_xor((int)mm, msk));
                o[j] = mm;
                if (a == mm) { a = b; b = 0xFFFFFFFFu; }
            }
            if (lr == 0) {
                const int prow = p0 + wm * 32 + m * 16 + g * 4 + r;
                u32x4 ov; ov[0] = o[0]; ov[1] = o[1]; ov[2] = o[2]; ov[3] = o[3];
                *(u32x4*)&best4[((size_t)prow * 16 + hs) * 4] = ov;
            }
        }
    }
}

// ---------------------------------------------------------------------------
// FUSED exact + output: one wg per 32 pixels, 256 threads. (R25, unchanged)
// ---------------------------------------------------------------------------
__global__ __launch_bounds__(256) void vq_out_kernel(
    const float* __restrict__ z, const float* __restrict__ cb,
    const float* __restrict__ e2, const u32* __restrict__ best4,
    float* __restrict__ out, float* __restrict__ idxf,
    float* __restrict__ loss)
{
    __shared__ float zb[32][260];   // 33.3 KB  z block (exact dots + loss)
    __shared__ float zq[32][257];   // 32.9 KB  gathered codebook rows
    __shared__ u64  sfinal[32];
    __shared__ int  nidx[32];
    __shared__ u32  work[2048];     // (px<<13)|n  (hard cap 32*64)
    __shared__ u32  scans[512];     // (px<<4)|hs  (hard cap 32*16)
    __shared__ int  nwork, nscan;

    const int tid = threadIdx.x;
    const int p0  = blockIdx.x * 32;
    const int bb  = p0 >> 10, hw0 = p0 & 1023;

    if (tid == 0) { nwork = 0; nscan = 0; }
    if (tid < 32) sfinal[tid] = ~0ULL;
    __syncthreads();

    // Phase A ------------------------------------------------------------
    {
        const int pix = tid >> 3;          // 0..31
        const int hp  = (tid & 7) * 2;     // this thread's 2 half-slices
        const u32* src = &best4[((size_t)(p0 + pix) * 16 + hp) * 4];
        const u32x4 kv0 = *(const u32x4*)(src);
        const u32x4 kv1 = *(const u32x4*)(src + 4);
        u32 lmin = min(min(kv0[0], kv0[1]), min(kv0[2], kv0[3]));
        lmin = min(lmin, min(min(kv1[0], kv1[1]), min(kv1[2], kv1[3])));
        u32 mn = lmin;
        #pragma unroll
        for (int m = 1; m < 8; m <<= 1) mn = min(mn, (u32)__shfl_xor((int)mn, m));
        const float thr = kval(mn) + DELTA;
        int c8 = 0;
        #pragma unroll
        for (int j = 0; j < 4; ++j) c8 += (kval(kv0[j]) <= thr) ? 1 : 0;
        #pragma unroll
        for (int j = 0; j < 4; ++j) c8 += (kval(kv1[j]) <= thr) ? 1 : 0;
        int cnt = c8;
        #pragma unroll
        for (int m = 1; m < 8; m <<= 1) cnt += __shfl_xor(cnt, m);
        const int s0 = (kval(kv0[3]) <= thr) ? 1 : 0;
        const int s1 = (kval(kv1[3]) <= thr) ? 1 : 0;
        int anysusp = s0 + s1;
        #pragma unroll
        for (int m = 1; m < 8; m <<= 1) anysusp += __shfl_xor(anysusp, m);

        if (cnt == 1 && anysusp == 0) {
            if (lmin == mn) sfinal[pix] = (u64)(mn & 8191u);
        } else {
            if (c8 > 0) {
                const int base = atomicAdd(&nwork, c8);
                int k = 0;
                #pragma unroll
                for (int j = 0; j < 4; ++j)
                    if (kval(kv0[j]) <= thr)
                        work[base + (k++)] = ((u32)pix << 13) | (kv0[j] & 8191u);
                #pragma unroll
                for (int j = 0; j < 4; ++j)
                    if (kval(kv1[j]) <= thr)
                        work[base + (k++)] = ((u32)pix << 13) | (kv1[j] & 8191u);
            }
            if (s0) scans[atomicAdd(&nscan, 1)] = ((u32)pix << 4) | (u32)hp;
            if (s1) scans[atomicAdd(&nscan, 1)] = ((u32)pix << 4) | (u32)(hp + 1);
        }
    }
    __syncthreads();

    // Stage zb (always -- feeds exact dots AND the loss) -------------------
    #pragma unroll
    for (int i = 0; i < 32; ++i) {
        const int idx = i * 256 + tid;
        const int c = idx >> 5, px = idx & 31;
        zb[px][c] = z[(size_t)bb * BCHW + (size_t)c * HW + hw0 + px];
    }
    __syncthreads();

    const int nw = nwork, ns = nscan;

    // Phase C: one thread per passer candidate ----------------------------
    for (int i = tid; i < nw; i += 256) {
        const u32 e = work[i];
        const int px = (int)(e >> 13), n = (int)(e & 8191u);
        const float* er = cb + (size_t)n * KD;
        float acc = 0.f;
        #pragma unroll 4
        for (int k = 0; k < KD; k += 4) {
            const f32x4 zv = *(const f32x4*)&zb[px][k];
            const f32x4 ev = *(const f32x4*)(er + k);
            acc += zv[0]*ev[0] + zv[1]*ev[1] + zv[2]*ev[2] + zv[3]*ev[3];
        }
        const float s = 0.5f * e2[n] - acc;
        atomicMin(&sfinal[px], ((u64)fkey(s) << 32) | (u32)n);
    }

    // Phase D: suspect half-slice scans (rare) ----------------------------
    for (int si = 0; si < ns; ++si) {
        const u32 e = scans[si];
        const int px = (int)(e >> 4), hx = (int)(e & 15u);
        u64 bku = ~0ULL;
        #pragma unroll
        for (int h = 0; h < 2; ++h) {
            const int ci = tid + h * 256;
            const int n = (hx >> 1) * 1024 + (ci >> 6) * 128
                        + (hx & 1) * 64 + (ci & 63);
            const float* er = cb + (size_t)n * KD;
            float acc = 0.f;
            #pragma unroll 4
            for (int k = 0; k < KD; k += 4) {
                const f32x4 zv = *(const f32x4*)&zb[px][k];
                const f32x4 ev = *(const f32x4*)(er + k);
                acc += zv[0]*ev[0] + zv[1]*ev[1] + zv[2]*ev[2] + zv[3]*ev[3];
            }
            const float s = 0.5f * e2[n] - acc;
            const u64 pk = ((u64)fkey(s) << 32) | (u32)n;
            bku = min(bku, pk);
        }
        #pragma unroll
        for (int m = 1; m < 64; m <<= 1) {
            const u64 o = (u64)__shfl_xor((long long)bku, m);
            bku = min(bku, o);
        }
        if ((tid & 63) == 0) atomicMin(&sfinal[px], bku);
    }
    __syncthreads();

    // Winners -> idx output ------------------------------------------------
    if (tid < 32) {
        const int n = (int)((u32)sfinal[tid] & 8191u);
        nidx[tid] = n;
        idxf[p0 + tid] = (float)n;
    }
    __syncthreads();

    // Gather 32 codebook rows coalesced -----------------------------------
    {
        const int r = tid >> 3, i = tid & 7;
        const float* src = cb + (size_t)nidx[r] * KD;
        #pragma unroll
        for (int j = 0; j < 8; ++j) {
            const int col = i * 4 + j * 32;
            const f32x4 v = *(const f32x4*)(src + col);
            zq[r][col + 0] = v[0]; zq[r][col + 1] = v[1];
            zq[r][col + 2] = v[2]; zq[r][col + 3] = v[3];
        }
    }
    __syncthreads();

    // Channel-first z_q write + loss (z from zb) --------------------------
    const int p4 = (tid & 7) * 4;
    const int cg = tid >> 3;
    float ls = 0.f;
    #pragma unroll
    for (int ii = 0; ii < 8; ++ii) {
        const int c = cg + 32 * ii;
        const size_t e = (size_t)bb * BCHW + (size_t)c * HW + hw0 + p4;
        f32x4 v;
        v[0] = zq[p4 + 0][c]; v[1] = zq[p4 + 1][c];
        v[2] = zq[p4 + 2][c]; v[3] = zq[p4 + 3][c];
        *(f32x4*)(out + e) = v;
        const float d0 = v[0] - zb[p4 + 0][c], d1 = v[1] - zb[p4 + 1][c];
        const float d2 = v[2] - zb[p4 + 2][c], d3 = v[3] - zb[p4 + 3][c];
        ls += d0 * d0 + d1 * d1 + d2 * d2 + d3 * d3;
    }
    #pragma unroll
    for (int m = 1; m < 64; m <<= 1) ls += __shfl_xor(ls, m);
    if ((tid & 63) == 0) atomicAdd(loss, ls * (1.25f / 4194304.f));
}

// ---------------------------------------------------------------------------
extern "C" void kernel_launch(void* const* d_in, const int* in_sizes, int n_in,
                              void* d_out, int out_size, void* d_ws, size_t ws_size,
                              hipStream_t stream) {
    const float* z  = (const float*)d_in[0];
    const float* cb = (const float*)d_in[1];
    float* out  = (float*)d_out;
    float* idxf = out + 4194304;
    float* loss = out + 4210688;
    // scratch inside the z_q region of d_out (fully overwritten at the end):
    char* ob = (char*)d_out;
    short* zh    = (short*)ob;                    // [0 .. 8MB)   bf16 z [p][k]
    short* eh    = (short*)(ob + 8388608);        // [8 .. 12MB)  bf16 codebook
    u32*   best4 = (u32*)(ob + 12582912);         // [12 .. 16MB) 16384 x 16 x 4 u32

    float* e2 = (float*)d_ws;                // 32 KB

    hipMemsetAsync(loss, 0, 4, stream);

    vq_prep2<<<3072, 256, 0, stream>>>(cb, z, eh, e2, zh);
    vq_gemm<<<dim3(NPIX / 128, NE / (NT * 128)), 512, 0, stream>>>(zh, eh, best4);
    vq_out_kernel<<<NPIX / 32, 256, 0, stream>>>(z, cb, e2, best4, out, idxf, loss);
}